// Round 1
// baseline (1083.491 us; speedup 1.0000x reference)
//
#include <hip/hip_runtime.h>
#include <stdint.h>

#define B_ 8
#define D_ 256
#define T_ 2048
#define K_ 8192
#define N_ (B_*T_)   // 16384

// ---------------- workspace layout ----------------
// best: u64[N]   off 0         (131072 B)
// cs:   int[K]   off 131072    (32768 B)
// dw:   f32[K*D] off 163840    (8388608 B)
// sse:  f32[K]   off 8552448   (32768 B)
// ssx:  f32[N]   off 8585216   (65536 B)
// total 8650752 B

// sum of squares of each embedding row (match: sum(emb**2, axis=1))
__global__ __launch_bounds__(256) void sse_kernel(const float* __restrict__ E,
                                                  float* __restrict__ sse) {
    int row  = blockIdx.x * 4 + (threadIdx.x >> 6);
    int lane = threadIdx.x & 63;
    float4 v = *(const float4*)(E + (size_t)row * D_ + lane * 4);
    // avoid fma-contraction: squares rounded individually like the reference
    float s = __fadd_rn(__fadd_rn(__fmul_rn(v.x, v.x), __fmul_rn(v.y, v.y)),
                        __fadd_rn(__fmul_rn(v.z, v.z), __fmul_rn(v.w, v.w)));
    #pragma unroll
    for (int off = 32; off > 0; off >>= 1) s += __shfl_down(s, off);
    if (lane == 0) sse[row] = s;
}

// sum of squares of each flattened x row: ssx[b*T+t] = sum_d x[b][d][t]^2
__global__ __launch_bounds__(256) void ssx_kernel(const float* __restrict__ x,
                                                  float* __restrict__ ssx) {
    int bt = blockIdx.x;                 // 0..63
    int b  = bt >> 3;
    int t  = ((bt & 7) << 8) + threadIdx.x;
    const float* xp = x + (size_t)b * D_ * T_ + t;
    float s = 0.f;
    for (int d = 0; d < D_; d++) {
        float v = xp[(size_t)d * T_];
        s = __fadd_rn(s, __fmul_rn(v, v));   // serial d-order, no contraction
    }
    ssx[b * T_ + t] = s;
}

// -------- fused distance + argmin --------
#define TM 128
#define TN 128
#define DK 32
#define NCT 16    // code tiles per block -> 2048 codes per block

__global__ __launch_bounds__(256) void dist_kernel(
    const float* __restrict__ x, const float* __restrict__ E,
    const float* __restrict__ ssx, const float* __restrict__ sse,
    unsigned long long* __restrict__ best)
{
    __shared__ float Xs[DK][TM];
    __shared__ float Es[DK][TN];
    __shared__ unsigned long long red[TM * 16];

    const int tid = threadIdx.x;
    const int ty  = tid >> 4;     // 0..15
    const int tx  = tid & 15;     // 0..15

    const int row0 = blockIdx.x * TM;           // tile never crosses b (TM|T_)
    const int b    = row0 / T_;
    const int t0   = row0 % T_;
    const float* xblk = x + (size_t)b * D_ * T_ + t0;  // (d,r) -> xblk[d*T_+r]

    unsigned long long bst[8];
    #pragma unroll
    for (int i = 0; i < 8; i++) bst[i] = ~0ull;

    float ssx_r[8];
    #pragma unroll
    for (int i = 0; i < 8; i++) ssx_r[i] = ssx[row0 + ty * 8 + i];

    for (int ct = 0; ct < NCT; ct++) {
        const int c0 = (blockIdx.y * NCT + ct) * TN;

        float acc[8][8];
        #pragma unroll
        for (int i = 0; i < 8; i++)
            #pragma unroll
            for (int j = 0; j < 8; j++) acc[i][j] = 0.f;

        for (int dc = 0; dc < D_ / DK; dc++) {
            // stage X tile: [DK][TM], coalesced along t
            {
                int r = (tid & 31) * 4;
                int dbase = tid >> 5;            // 0..7
                #pragma unroll
                for (int dd = 0; dd < 4; dd++) {
                    int d = dbase + dd * 8;
                    float4 g = *(const float4*)(xblk + (size_t)(dc * DK + d) * T_ + r);
                    *(float4*)&Xs[d][r] = g;
                }
            }
            // stage E tile transposed: Es[d][c]
            {
                int c = tid >> 1;                // 0..127
                int dbase = (tid & 1) * 16;
                const float* ep = E + (size_t)(c0 + c) * D_ + dc * DK + dbase;
                float4 g0 = *(const float4*)(ep + 0);
                float4 g1 = *(const float4*)(ep + 4);
                float4 g2 = *(const float4*)(ep + 8);
                float4 g3 = *(const float4*)(ep + 12);
                Es[dbase + 0][c] = g0.x;  Es[dbase + 1][c] = g0.y;
                Es[dbase + 2][c] = g0.z;  Es[dbase + 3][c] = g0.w;
                Es[dbase + 4][c] = g1.x;  Es[dbase + 5][c] = g1.y;
                Es[dbase + 6][c] = g1.z;  Es[dbase + 7][c] = g1.w;
                Es[dbase + 8][c] = g2.x;  Es[dbase + 9][c] = g2.y;
                Es[dbase +10][c] = g2.z;  Es[dbase +11][c] = g2.w;
                Es[dbase +12][c] = g3.x;  Es[dbase +13][c] = g3.y;
                Es[dbase +14][c] = g3.z;  Es[dbase +15][c] = g3.w;
            }
            __syncthreads();

            #pragma unroll 8
            for (int kk = 0; kk < DK; kk++) {
                float a[8], bv[8];
                *(float4*)&a[0]  = *(const float4*)&Xs[kk][ty * 8];
                *(float4*)&a[4]  = *(const float4*)&Xs[kk][ty * 8 + 4];
                *(float4*)&bv[0] = *(const float4*)&Es[kk][tx * 8];
                *(float4*)&bv[4] = *(const float4*)&Es[kk][tx * 8 + 4];
                #pragma unroll
                for (int i = 0; i < 8; i++)
                    #pragma unroll
                    for (int j = 0; j < 8; j++)
                        acc[i][j] = fmaf(a[i], bv[j], acc[i][j]);
            }
            __syncthreads();
        }

        // distances + running packed argmin (ties -> lower index, like np)
        float sse_c[8];
        #pragma unroll
        for (int j = 0; j < 8; j++) sse_c[j] = sse[c0 + tx * 8 + j];

        #pragma unroll
        for (int i = 0; i < 8; i++) {
            #pragma unroll
            for (int j = 0; j < 8; j++) {
                float dist = (ssx_r[i] + sse_c[j]) - 2.0f * acc[i][j];
                unsigned long long p =
                    ((unsigned long long)__float_as_uint(dist) << 32)
                    | (unsigned long long)(unsigned)(c0 + tx * 8 + j);
                if (p < bst[i]) bst[i] = p;
            }
        }
    }

    // cross-tx reduction (16 candidates per row) then one atomicMin per row
    #pragma unroll
    for (int i = 0; i < 8; i++) red[(ty * 8 + i) * 16 + tx] = bst[i];
    __syncthreads();
    if (tid < TM) {
        unsigned long long m = red[tid * 16];
        #pragma unroll
        for (int j = 1; j < 16; j++) {
            unsigned long long v = red[tid * 16 + j];
            if (v < m) m = v;
        }
        atomicMin(best + row0 + tid, m);
    }
}

// gather codebook -> out0/out2, copy x -> out1, accumulate cluster stats
__global__ __launch_bounds__(256) void scatter_kernel(
    const float* __restrict__ x, const float* __restrict__ E,
    const unsigned long long* __restrict__ best,
    float* __restrict__ out, int* __restrict__ cs, float* __restrict__ dw)
{
    int bt = blockIdx.x;                  // 0..63
    int b  = bt >> 3;
    int t  = ((bt & 7) << 8) + threadIdx.x;
    int n  = b * T_ + t;
    unsigned idx = (unsigned)(best[n] & 0xffffffffu);
    int dchunk = blockIdx.y;              // 0..3 (64 d's each)

    if (dchunk == 0) atomicAdd(cs + idx, 1);

    const float* ep = E + (size_t)idx * D_;
    const float* xp = x + (size_t)b * D_ * T_ + t;
    float* o0 = out + (size_t)b * D_ * T_ + t;
    float* o1 = o0 + (size_t)N_ * D_;
    float* o2 = o1 + (size_t)N_ * D_;

    for (int dd = 0; dd < 64; dd++) {
        int d = dchunk * 64 + dd;
        float e  = ep[d];
        float xv = xp[(size_t)d * T_];
        o0[(size_t)d * T_] = e;
        o1[(size_t)d * T_] = xv;
        o2[(size_t)d * T_] = e;
        atomicAdd(dw + (size_t)idx * D_ + d, xv);
    }
}

// new_embeddings = ema_dw / ema_cs  (counter==1 collapse)
__global__ __launch_bounds__(256) void finalize_kernel(
    const int* __restrict__ cs, const float* __restrict__ dw,
    float* __restrict__ out3)
{
    int k = blockIdx.x;
    int d = threadIdx.x;
    const float C = 0.00999999977648258209228515625f;  // float(1.0-0.99)
    float c   = (float)cs[k];
    float ecs = (c * C) / C;
    float edw = (dw[(size_t)k * D_ + d] * C) / C;
    float n = 16384.0f;
    float denom = (ecs + 1e-5f) / (n + (float)K_ * 1e-5f) * n;
    out3[(size_t)k * D_ + d] = edw / denom;
}

extern "C" void kernel_launch(void* const* d_in, const int* in_sizes, int n_in,
                              void* d_out, int out_size, void* d_ws, size_t ws_size,
                              hipStream_t stream) {
    const float* x = (const float*)d_in[0];
    const float* E = (const float*)d_in[1];
    float* out = (float*)d_out;

    char* ws = (char*)d_ws;
    unsigned long long* best = (unsigned long long*)(ws);
    int*   cs  = (int*)  (ws + 131072);
    float* dw  = (float*)(ws + 163840);
    float* sse = (float*)(ws + 8552448);
    float* ssx = (float*)(ws + 8585216);

    hipMemsetAsync(best, 0xFF, (size_t)N_ * 8, stream);
    hipMemsetAsync(cs, 0, 32768 + 8388608, stream);   // cs + dw contiguous

    sse_kernel<<<K_ / 4, 256, 0, stream>>>(E, sse);
    ssx_kernel<<<N_ / 256, 256, 0, stream>>>(x, ssx);
    dist_kernel<<<dim3(N_ / TM, K_ / (TN * NCT)), 256, 0, stream>>>(x, E, ssx, sse, best);
    scatter_kernel<<<dim3(N_ / 256, 4), 256, 0, stream>>>(x, E, best, out, cs, dw);
    finalize_kernel<<<K_, 256, 0, stream>>>(cs, dw, out + 3 * (size_t)N_ * D_);
}

// Round 2
// 512.018 us; speedup vs baseline: 2.1161x; 2.1161x over previous
//
#include <hip/hip_runtime.h>
#include <stdint.h>

#define B_ 8
#define D_ 256
#define T_ 2048
#define K_ 8192
#define N_ (B_*T_)   // 16384

typedef __attribute__((ext_vector_type(8))) __bf16 bf16x8;
typedef __attribute__((ext_vector_type(4))) __bf16 bf16x4;
typedef __attribute__((ext_vector_type(2))) __bf16 bf16x2;
typedef __attribute__((ext_vector_type(4))) float f32x4;

#define GLD_TO_LDS16(gsrc, ldst) \
  __builtin_amdgcn_global_load_lds((__attribute__((address_space(1))) const void*)(gsrc), \
                                   (__attribute__((address_space(3))) void*)(ldst), 16, 0, 0)

// ---------------- workspace layout (unchanged from round 1, proven to fit) --
// best: u64[N]   off 0         (131072 B)
// cs:   int[K]   off 131072    (32768 B)
// dw:   f32[K*D] off 163840    (8388608 B)
// sse:  f32[K]   off 8552448   (32768 B)
// ssx:  f32[N]   off 8585216   (65536 B)
// bf16 split arrays live in d_out (out0 region: X_hi/X_lo exactly 16 MB;
// out2 region: E_hi/E_lo 8 MB) — free scratch until scatter_kernel runs.

// sum of squares of each embedding row (reference order preserved)
__global__ __launch_bounds__(256) void sse_kernel(const float* __restrict__ E,
                                                  float* __restrict__ sse) {
    int row  = blockIdx.x * 4 + (threadIdx.x >> 6);
    int lane = threadIdx.x & 63;
    float4 v = *(const float4*)(E + (size_t)row * D_ + lane * 4);
    float s = __fadd_rn(__fadd_rn(__fmul_rn(v.x, v.x), __fmul_rn(v.y, v.y)),
                        __fadd_rn(__fmul_rn(v.z, v.z), __fadd_rn(__fmul_rn(v.w, v.w), 0.f)));
    #pragma unroll
    for (int off = 32; off > 0; off >>= 1) s += __shfl_down(s, off);
    if (lane == 0) sse[row] = s;
}

// ssx[b*T+t] = sum_d x[b][d][t]^2, serial d-order
__global__ __launch_bounds__(256) void ssx_kernel(const float* __restrict__ x,
                                                  float* __restrict__ ssx) {
    int bt = blockIdx.x;
    int b  = bt >> 3;
    int t  = ((bt & 7) << 8) + threadIdx.x;
    const float* xp = x + (size_t)b * D_ * T_ + t;
    float s = 0.f;
    for (int d = 0; d < D_; d++) {
        float v = xp[(size_t)d * T_];
        s = __fadd_rn(s, __fmul_rn(v, v));
    }
    ssx[b * T_ + t] = s;
}

// split E [K][D] f32 -> E_hi/E_lo bf16 (row-major, no transpose)
__global__ __launch_bounds__(256) void prep_e_kernel(const float* __restrict__ E,
                                                     __bf16* __restrict__ Eh,
                                                     __bf16* __restrict__ El) {
    size_t i4 = (size_t)blockIdx.x * 256 + threadIdx.x;   // one float4 each
    float4 v = *(const float4*)(E + i4 * 4);
    __bf16 h0 = (__bf16)v.x, h1 = (__bf16)v.y, h2 = (__bf16)v.z, h3 = (__bf16)v.w;
    __bf16 l0 = (__bf16)(v.x - (float)h0), l1 = (__bf16)(v.y - (float)h1);
    __bf16 l2 = (__bf16)(v.z - (float)h2), l3 = (__bf16)(v.w - (float)h3);
    bf16x4 hv = {h0, h1, h2, h3};
    bf16x4 lv = {l0, l1, l2, l3};
    *(bf16x4*)(Eh + i4 * 4) = hv;
    *(bf16x4*)(El + i4 * 4) = lv;
}

// transpose+split x [B][D][T] f32 -> X_hi/X_lo [N][D] bf16 row-major
__global__ __launch_bounds__(256) void prep_x_kernel(const float* __restrict__ x,
                                                     __bf16* __restrict__ Xh,
                                                     __bf16* __restrict__ Xl) {
    __shared__ float tile[64][65];
    int bidx = blockIdx.x;            // b(8) x dblk(4) x tblk(32)
    int b    = bidx >> 7;
    int dblk = (bidx >> 5) & 3;
    int tblk = bidx & 31;
    int d0 = dblk * 64, t0 = tblk * 64;
    const float* xp = x + (size_t)b * D_ * T_;

    {
        int tl = threadIdx.x & 63, th = threadIdx.x >> 6;
        #pragma unroll
        for (int i = 0; i < 16; i++) {
            int d = i * 4 + th;
            tile[d][tl] = xp[(size_t)(d0 + d) * T_ + t0 + tl];
        }
    }
    __syncthreads();
    {
        int dp = (threadIdx.x & 31) * 2, th = threadIdx.x >> 5;   // 2 d's per thread
        #pragma unroll
        for (int i = 0; i < 8; i++) {
            int t = i * 8 + th;
            float v0 = tile[dp][t], v1 = tile[dp + 1][t];
            __bf16 h0 = (__bf16)v0, h1 = (__bf16)v1;
            __bf16 q0 = (__bf16)(v0 - (float)h0), q1 = (__bf16)(v1 - (float)h1);
            size_t n = (size_t)b * T_ + t0 + t;
            bf16x2 hv = {h0, h1};
            bf16x2 lv = {q0, q1};
            *(bf16x2*)(Xh + n * D_ + d0 + dp) = hv;
            *(bf16x2*)(Xl + n * D_ + d0 + dp) = lv;
        }
    }
}

// -------- MFMA distance + argmin: 128 rows x 128 codes per block --------
// A-operand = codes (M), B-operand = x-rows (N); D[code][row].
// 3-product bf16 emulation of the fp32 dot.
__global__ __launch_bounds__(256) void dist_kernel(
    const __bf16* __restrict__ Eh, const __bf16* __restrict__ El,
    const __bf16* __restrict__ Xh, const __bf16* __restrict__ Xl,
    const float* __restrict__ ssx, const float* __restrict__ sse,
    unsigned long long* __restrict__ best)
{
    __shared__ __bf16 Ah[128 * 32];
    __shared__ __bf16 Al[128 * 32];
    __shared__ __bf16 Bh[128 * 32];
    __shared__ __bf16 Bl[128 * 32];

    const int tid = threadIdx.x;
    const int l   = tid & 63;
    const int w   = tid >> 6;       // wave 0..3
    const int wm  = w >> 1;         // code half
    const int wn  = w & 1;          // row half

    const int r0 = blockIdx.x * 128;   // x-row block
    const int c0 = blockIdx.y * 128;   // code block

    f32x4 acc[4][4];
    #pragma unroll
    for (int i = 0; i < 4; i++)
        #pragma unroll
        for (int j = 0; j < 4; j++) acc[i][j] = (f32x4)0.f;

    // staging: each wave stages 32 rows (2 x 16-row instrs) of each buffer.
    const int srow = w * 32 + (l >> 2);          // rows covered (and +16)
    const int selm = (l & 3) * 8;                // element offset within 32-k row
    const __bf16* gAh = Eh + (size_t)(c0 + srow) * D_ + selm;
    const __bf16* gAl = El + (size_t)(c0 + srow) * D_ + selm;
    const __bf16* gBh = Xh + (size_t)(r0 + srow) * D_ + selm;
    const __bf16* gBl = Xl + (size_t)(r0 + srow) * D_ + selm;
    __bf16* dA0 = Ah + (w * 32) * 32;        // wave-uniform LDS bases
    __bf16* dA1 = Ah + (w * 32 + 16) * 32;
    __bf16* eA0 = Al + (w * 32) * 32;
    __bf16* eA1 = Al + (w * 32 + 16) * 32;
    __bf16* dB0 = Bh + (w * 32) * 32;
    __bf16* dB1 = Bh + (w * 32 + 16) * 32;
    __bf16* eB0 = Bl + (w * 32) * 32;
    __bf16* eB1 = Bl + (w * 32 + 16) * 32;

    const int ka = (l >> 4) * 8;                 // k-slot within fragment

    for (int kc = 0; kc < 8; kc++) {
        const int ko = kc * 32;
        GLD_TO_LDS16(gAh + ko,            dA0);
        GLD_TO_LDS16(gAh + ko + 16 * D_,  dA1);
        GLD_TO_LDS16(gAl + ko,            eA0);
        GLD_TO_LDS16(gAl + ko + 16 * D_,  eA1);
        GLD_TO_LDS16(gBh + ko,            dB0);
        GLD_TO_LDS16(gBh + ko + 16 * D_,  dB1);
        GLD_TO_LDS16(gBl + ko,            eB0);
        GLD_TO_LDS16(gBl + ko + 16 * D_,  eB1);
        __syncthreads();   // drains vmcnt then barrier

        bf16x8 ah[4], al[4], bh[4], bl[4];
        #pragma unroll
        for (int i = 0; i < 4; i++) {
            int arow = wm * 64 + i * 16 + (l & 15);
            int brow = wn * 64 + i * 16 + (l & 15);
            ah[i] = *(const bf16x8*)&Ah[arow * 32 + ka];
            al[i] = *(const bf16x8*)&Al[arow * 32 + ka];
            bh[i] = *(const bf16x8*)&Bh[brow * 32 + ka];
            bl[i] = *(const bf16x8*)&Bl[brow * 32 + ka];
        }
        #pragma unroll
        for (int i = 0; i < 4; i++)
            #pragma unroll
            for (int j = 0; j < 4; j++) {
                acc[i][j] = __builtin_amdgcn_mfma_f32_16x16x32_bf16(al[i], bh[j], acc[i][j], 0, 0, 0);
                acc[i][j] = __builtin_amdgcn_mfma_f32_16x16x32_bf16(ah[i], bl[j], acc[i][j], 0, 0, 0);
                acc[i][j] = __builtin_amdgcn_mfma_f32_16x16x32_bf16(ah[i], bh[j], acc[i][j], 0, 0, 0);
            }
        __syncthreads();   // protect LDS before next stage
    }

    // epilogue: dist = (ssx + sse) - 2*dot, packed-u64 argmin (ties -> low idx)
    float sse_c[4][4];
    #pragma unroll
    for (int i = 0; i < 4; i++) {
        int cbase = c0 + wm * 64 + i * 16 + (l >> 4) * 4;
        #pragma unroll
        for (int r = 0; r < 4; r++) sse_c[i][r] = sse[cbase + r];
    }
    #pragma unroll
    for (int j = 0; j < 4; j++) {
        int row = r0 + wn * 64 + j * 16 + (l & 15);
        float sx = ssx[row];
        unsigned long long m = ~0ull;
        #pragma unroll
        for (int i = 0; i < 4; i++) {
            int cbase = c0 + wm * 64 + i * 16 + (l >> 4) * 4;
            #pragma unroll
            for (int r = 0; r < 4; r++) {
                float dist = (sx + sse_c[i][r]) - 2.0f * acc[i][j][r];
                unsigned long long p =
                    ((unsigned long long)__float_as_uint(dist) << 32)
                    | (unsigned long long)(unsigned)(cbase + r);
                if (p < m) m = p;
            }
        }
        unsigned long long o;
        o = __shfl_xor(m, 16); if (o < m) m = o;
        o = __shfl_xor(m, 32); if (o < m) m = o;
        if ((l >> 4) == 0) atomicMin(best + row, m);
    }
}

// gather codebook -> out0/out2, copy x -> out1, accumulate cluster stats
__global__ __launch_bounds__(256) void scatter_kernel(
    const float* __restrict__ x, const float* __restrict__ E,
    const unsigned long long* __restrict__ best,
    float* __restrict__ out, int* __restrict__ cs, float* __restrict__ dw)
{
    int bt = blockIdx.x;
    int b  = bt >> 3;
    int t  = ((bt & 7) << 8) + threadIdx.x;
    int n  = b * T_ + t;
    unsigned idx = (unsigned)(best[n] & 0xffffffffu);
    int dchunk = blockIdx.y;

    if (dchunk == 0) atomicAdd(cs + idx, 1);

    const float* ep = E + (size_t)idx * D_;
    const float* xp = x + (size_t)b * D_ * T_ + t;
    float* o0 = out + (size_t)b * D_ * T_ + t;
    float* o1 = o0 + (size_t)N_ * D_;
    float* o2 = o1 + (size_t)N_ * D_;

    for (int dd = 0; dd < 64; dd++) {
        int d = dchunk * 64 + dd;
        float e  = ep[d];
        float xv = xp[(size_t)d * T_];
        o0[(size_t)d * T_] = e;
        o1[(size_t)d * T_] = xv;
        o2[(size_t)d * T_] = e;
        atomicAdd(dw + (size_t)idx * D_ + d, xv);
    }
}

__global__ __launch_bounds__(256) void finalize_kernel(
    const int* __restrict__ cs, const float* __restrict__ dw,
    float* __restrict__ out3)
{
    int k = blockIdx.x;
    int d = threadIdx.x;
    const float C = 0.00999999977648258209228515625f;
    float c   = (float)cs[k];
    float ecs = (c * C) / C;
    float edw = (dw[(size_t)k * D_ + d] * C) / C;
    float n = 16384.0f;
    float denom = (ecs + 1e-5f) / (n + (float)K_ * 1e-5f) * n;
    out3[(size_t)k * D_ + d] = edw / denom;
}

extern "C" void kernel_launch(void* const* d_in, const int* in_sizes, int n_in,
                              void* d_out, int out_size, void* d_ws, size_t ws_size,
                              hipStream_t stream) {
    const float* x = (const float*)d_in[0];
    const float* E = (const float*)d_in[1];
    float* out = (float*)d_out;

    char* ws = (char*)d_ws;
    unsigned long long* best = (unsigned long long*)(ws);
    int*   cs  = (int*)  (ws + 131072);
    float* dw  = (float*)(ws + 163840);
    float* sse = (float*)(ws + 8552448);
    float* ssx = (float*)(ws + 8585216);

    // bf16 split arrays live in d_out regions (scratch until scatter runs):
    // out0 region: X_hi | X_lo (exactly 16 MB); out2 region: E_hi | E_lo (8 MB)
    __bf16* Xh = (__bf16*)out;
    __bf16* Xl = Xh + (size_t)N_ * D_;
    __bf16* Eh = (__bf16*)(out + 2 * (size_t)N_ * D_);
    __bf16* El = Eh + (size_t)K_ * D_;

    hipMemsetAsync(best, 0xFF, (size_t)N_ * 8, stream);
    hipMemsetAsync(cs, 0, 32768 + 8388608, stream);   // cs + dw contiguous

    sse_kernel<<<K_ / 4, 256, 0, stream>>>(E, sse);
    ssx_kernel<<<N_ / 256, 256, 0, stream>>>(x, ssx);
    prep_e_kernel<<<(K_ * D_) / 1024, 256, 0, stream>>>(E, Eh, El);
    prep_x_kernel<<<1024, 256, 0, stream>>>(x, Xh, Xl);
    dist_kernel<<<dim3(N_ / 128, K_ / 128), 256, 0, stream>>>(Eh, El, Xh, Xl, ssx, sse, best);
    scatter_kernel<<<dim3(N_ / 256, 4), 256, 0, stream>>>(x, E, best, out, cs, dw);
    finalize_kernel<<<K_, 256, 0, stream>>>(cs, dw, out + 3 * (size_t)N_ * D_);
}

// Round 3
// 274.625 us; speedup vs baseline: 3.9453x; 1.8644x over previous
//
#include <hip/hip_runtime.h>
#include <stdint.h>

#define B_ 8
#define D_ 256
#define T_ 2048
#define K_ 8192
#define N_ (B_*T_)   // 16384

typedef __attribute__((ext_vector_type(8))) __bf16 bf16x8;
typedef __attribute__((ext_vector_type(4))) __bf16 bf16x4;
typedef __attribute__((ext_vector_type(2))) __bf16 bf16x2;
typedef __attribute__((ext_vector_type(4))) float f32x4;

#define GLD_TO_LDS16(gsrc, ldst) \
  __builtin_amdgcn_global_load_lds((__attribute__((address_space(1))) const void*)(gsrc), \
                                   (__attribute__((address_space(3))) void*)(ldst), 16, 0, 0)

// ---------------- workspace layout ----------------
// best: u64[N]   off 0         (131072 B)
// cs:   int[K]   off 131072    (32768 B)
// dw:   f32[K*D] off 163840    (8388608 B)
// sse:  f32[K]   off 8552448   (32768 B)
// ssx:  f32[N]   off 8585216   (65536 B)
// bf16 split arrays live in d_out (out0 region: X_hi/X_lo exactly 16 MB;
// out2 region: E_hi/E_lo 8 MB) — free scratch until scatter_kernel runs.

// split E -> bf16 hi/lo AND compute sse row sums (fused)
__global__ __launch_bounds__(256) void prep_e_kernel(const float* __restrict__ E,
                                                     __bf16* __restrict__ Eh,
                                                     __bf16* __restrict__ El,
                                                     float* __restrict__ sse) {
    int row  = blockIdx.x * 4 + (threadIdx.x >> 6);
    int lane = threadIdx.x & 63;
    float4 v = *(const float4*)(E + (size_t)row * D_ + lane * 4);
    __bf16 h0 = (__bf16)v.x, h1 = (__bf16)v.y, h2 = (__bf16)v.z, h3 = (__bf16)v.w;
    __bf16 l0 = (__bf16)(v.x - (float)h0), l1 = (__bf16)(v.y - (float)h1);
    __bf16 l2 = (__bf16)(v.z - (float)h2), l3 = (__bf16)(v.w - (float)h3);
    bf16x4 hv = {h0, h1, h2, h3};
    bf16x4 lv = {l0, l1, l2, l3};
    *(bf16x4*)(Eh + (size_t)row * D_ + lane * 4) = hv;
    *(bf16x4*)(El + (size_t)row * D_ + lane * 4) = lv;
    float s = __fadd_rn(__fadd_rn(__fmul_rn(v.x, v.x), __fmul_rn(v.y, v.y)),
                        __fadd_rn(__fmul_rn(v.z, v.z), __fmul_rn(v.w, v.w)));
    #pragma unroll
    for (int off = 32; off > 0; off >>= 1) s += __shfl_down(s, off);
    if (lane == 0) sse[row] = s;
}

// transpose+split x -> X_hi/X_lo [N][D] bf16 AND accumulate ssx (fused)
__global__ __launch_bounds__(256) void prep_x_kernel(const float* __restrict__ x,
                                                     __bf16* __restrict__ Xh,
                                                     __bf16* __restrict__ Xl,
                                                     float* __restrict__ ssx) {
    __shared__ float tile[64][65];
    __shared__ float part[64][4];
    int bidx = blockIdx.x;            // b(8) x dblk(4) x tblk(32)
    int b    = bidx >> 7;
    int dblk = (bidx >> 5) & 3;
    int tblk = bidx & 31;
    int d0 = dblk * 64, t0 = tblk * 64;
    const float* xp = x + (size_t)b * D_ * T_;

    {
        int tl = threadIdx.x & 63, th = threadIdx.x >> 6;
        float s = 0.f;
        #pragma unroll
        for (int i = 0; i < 16; i++) {
            int d = i * 4 + th;
            float v = xp[(size_t)(d0 + d) * T_ + t0 + tl];
            tile[d][tl] = v;
            s = __fadd_rn(s, __fmul_rn(v, v));
        }
        part[tl][th] = s;
    }
    __syncthreads();
    if (threadIdx.x < 64) {
        float tot = __fadd_rn(__fadd_rn(__fadd_rn(part[threadIdx.x][0],
                    part[threadIdx.x][1]), part[threadIdx.x][2]), part[threadIdx.x][3]);
        atomicAdd(ssx + b * T_ + t0 + threadIdx.x, tot);
    }
    {
        int dp = (threadIdx.x & 31) * 2, th = threadIdx.x >> 5;
        #pragma unroll
        for (int i = 0; i < 8; i++) {
            int t = i * 8 + th;
            float v0 = tile[dp][t], v1 = tile[dp + 1][t];
            __bf16 h0 = (__bf16)v0, h1 = (__bf16)v1;
            __bf16 q0 = (__bf16)(v0 - (float)h0), q1 = (__bf16)(v1 - (float)h1);
            size_t n = (size_t)b * T_ + t0 + t;
            bf16x2 hv = {h0, h1};
            bf16x2 lv = {q0, q1};
            *(bf16x2*)(Xh + n * D_ + d0 + dp) = hv;
            *(bf16x2*)(Xl + n * D_ + d0 + dp) = lv;
        }
    }
}

// -------- MFMA distance + argmin (UNCHANGED from round 2, proven) --------
__global__ __launch_bounds__(256) void dist_kernel(
    const __bf16* __restrict__ Eh, const __bf16* __restrict__ El,
    const __bf16* __restrict__ Xh, const __bf16* __restrict__ Xl,
    const float* __restrict__ ssx, const float* __restrict__ sse,
    unsigned long long* __restrict__ best)
{
    __shared__ __bf16 Ah[128 * 32];
    __shared__ __bf16 Al[128 * 32];
    __shared__ __bf16 Bh[128 * 32];
    __shared__ __bf16 Bl[128 * 32];

    const int tid = threadIdx.x;
    const int l   = tid & 63;
    const int w   = tid >> 6;
    const int wm  = w >> 1;
    const int wn  = w & 1;

    const int r0 = blockIdx.x * 128;
    const int c0 = blockIdx.y * 128;

    f32x4 acc[4][4];
    #pragma unroll
    for (int i = 0; i < 4; i++)
        #pragma unroll
        for (int j = 0; j < 4; j++) acc[i][j] = (f32x4)0.f;

    const int srow = w * 32 + (l >> 2);
    const int selm = (l & 3) * 8;
    const __bf16* gAh = Eh + (size_t)(c0 + srow) * D_ + selm;
    const __bf16* gAl = El + (size_t)(c0 + srow) * D_ + selm;
    const __bf16* gBh = Xh + (size_t)(r0 + srow) * D_ + selm;
    const __bf16* gBl = Xl + (size_t)(r0 + srow) * D_ + selm;
    __bf16* dA0 = Ah + (w * 32) * 32;
    __bf16* dA1 = Ah + (w * 32 + 16) * 32;
    __bf16* eA0 = Al + (w * 32) * 32;
    __bf16* eA1 = Al + (w * 32 + 16) * 32;
    __bf16* dB0 = Bh + (w * 32) * 32;
    __bf16* dB1 = Bh + (w * 32 + 16) * 32;
    __bf16* eB0 = Bl + (w * 32) * 32;
    __bf16* eB1 = Bl + (w * 32 + 16) * 32;

    const int ka = (l >> 4) * 8;

    for (int kc = 0; kc < 8; kc++) {
        const int ko = kc * 32;
        GLD_TO_LDS16(gAh + ko,            dA0);
        GLD_TO_LDS16(gAh + ko + 16 * D_,  dA1);
        GLD_TO_LDS16(gAl + ko,            eA0);
        GLD_TO_LDS16(gAl + ko + 16 * D_,  eA1);
        GLD_TO_LDS16(gBh + ko,            dB0);
        GLD_TO_LDS16(gBh + ko + 16 * D_,  dB1);
        GLD_TO_LDS16(gBl + ko,            eB0);
        GLD_TO_LDS16(gBl + ko + 16 * D_,  eB1);
        __syncthreads();

        bf16x8 ah[4], al[4], bh[4], bl[4];
        #pragma unroll
        for (int i = 0; i < 4; i++) {
            int arow = wm * 64 + i * 16 + (l & 15);
            int brow = wn * 64 + i * 16 + (l & 15);
            ah[i] = *(const bf16x8*)&Ah[arow * 32 + ka];
            al[i] = *(const bf16x8*)&Al[arow * 32 + ka];
            bh[i] = *(const bf16x8*)&Bh[brow * 32 + ka];
            bl[i] = *(const bf16x8*)&Bl[brow * 32 + ka];
        }
        #pragma unroll
        for (int i = 0; i < 4; i++)
            #pragma unroll
            for (int j = 0; j < 4; j++) {
                acc[i][j] = __builtin_amdgcn_mfma_f32_16x16x32_bf16(al[i], bh[j], acc[i][j], 0, 0, 0);
                acc[i][j] = __builtin_amdgcn_mfma_f32_16x16x32_bf16(ah[i], bl[j], acc[i][j], 0, 0, 0);
                acc[i][j] = __builtin_amdgcn_mfma_f32_16x16x32_bf16(ah[i], bh[j], acc[i][j], 0, 0, 0);
            }
        __syncthreads();
    }

    float sse_c[4][4];
    #pragma unroll
    for (int i = 0; i < 4; i++) {
        int cbase = c0 + wm * 64 + i * 16 + (l >> 4) * 4;
        #pragma unroll
        for (int r = 0; r < 4; r++) sse_c[i][r] = sse[cbase + r];
    }
    #pragma unroll
    for (int j = 0; j < 4; j++) {
        int row = r0 + wn * 64 + j * 16 + (l & 15);
        float sx = ssx[row];
        unsigned long long m = ~0ull;
        #pragma unroll
        for (int i = 0; i < 4; i++) {
            int cbase = c0 + wm * 64 + i * 16 + (l >> 4) * 4;
            #pragma unroll
            for (int r = 0; r < 4; r++) {
                float dist = (sx + sse_c[i][r]) - 2.0f * acc[i][j][r];
                unsigned long long p =
                    ((unsigned long long)__float_as_uint(dist) << 32)
                    | (unsigned long long)(unsigned)(cbase + r);
                if (p < m) m = p;
            }
        }
        unsigned long long o;
        o = __shfl_xor(m, 16); if (o < m) m = o;
        o = __shfl_xor(m, 32); if (o < m) m = o;
        if ((l >> 4) == 0) atomicMin(best + row, m);
    }
}

// tiled coalesced gather/copy/stats: block = 64 n's x 256 d's
__global__ __launch_bounds__(256) void scatter_kernel(
    const float* __restrict__ x, const float* __restrict__ E,
    const unsigned long long* __restrict__ best,
    float* __restrict__ out, int* __restrict__ cs, float* __restrict__ dw)
{
    __shared__ float tx[64][68];   // [d-local][t-local], stride 68 keeps 16B align
    __shared__ float te[64][68];   // [d-local][n-local]
    __shared__ int sidx[64];

    const int blk = blockIdx.x;          // 256 blocks
    const int b   = blk >> 5;
    const int t0  = (blk & 31) * 64;
    const int tid = threadIdx.x;
    const int n0  = b * T_ + t0;

    if (tid < 64) {
        int ix = (int)(best[n0 + tid] & 0xffffffffu);
        sidx[tid] = ix;
        atomicAdd(cs + ix, 1);
    }
    __syncthreads();

    const int t4   = (tid & 15) * 4;
    const int dg   = tid >> 4;           // 0..15
    const int l    = tid & 63;
    const int w    = tid >> 6;           // 0..3
    const int nsub = l >> 4;             // 0..3
    const int dl4  = (l & 15) * 4;

    float* o0 = out;
    float* o1 = out + (size_t)N_ * D_;
    float* o2 = out + 2 * (size_t)N_ * D_;

    for (int dc = 0; dc < 4; dc++) {
        const int d0 = dc * 64;
        // x tile load (coalesced float4) + write-through to o1 (= x copy)
        #pragma unroll
        for (int r = 0; r < 4; r++) {
            int d = r * 16 + dg;
            size_t gi = ((size_t)(b * D_ + d0 + d)) * T_ + t0 + t4;
            float4 v = *(const float4*)(x + gi);
            *(float4*)&tx[d][t4] = v;
            *(float4*)(o1 + gi) = v;
        }
        // E gather: lanes along d (coalesced 256B row segments)
        #pragma unroll
        for (int i = 0; i < 4; i++) {
            int nl  = w * 16 + i * 4 + nsub;
            int row = sidx[nl];
            float4 ev = *(const float4*)(E + (size_t)row * D_ + d0 + dl4);
            te[dl4 + 0][nl] = ev.x;
            te[dl4 + 1][nl] = ev.y;
            te[dl4 + 2][nl] = ev.z;
            te[dl4 + 3][nl] = ev.w;
        }
        __syncthreads();
        // o0/o2 writes (coalesced float4 along t)
        #pragma unroll
        for (int r = 0; r < 4; r++) {
            int d = r * 16 + dg;
            float4 v = *(const float4*)&te[d][t4];
            size_t gi = ((size_t)(b * D_ + d0 + d)) * T_ + t0 + t4;
            *(float4*)(o0 + gi) = v;
            *(float4*)(o2 + gi) = v;
        }
        // dw: coalesced 64-lane row atomics (lane = d, iterate n)
        #pragma unroll
        for (int i = 0; i < 16; i++) {
            int nl = w * 16 + i;
            atomicAdd(dw + (size_t)sidx[nl] * D_ + d0 + l, tx[l][nl]);
        }
        __syncthreads();
    }
}

__global__ __launch_bounds__(256) void finalize_kernel(
    const int* __restrict__ cs, const float* __restrict__ dw,
    float* __restrict__ out3)
{
    int k = blockIdx.x;
    int d = threadIdx.x;
    const float C = 0.00999999977648258209228515625f;
    float c   = (float)cs[k];
    float ecs = (c * C) / C;
    float edw = (dw[(size_t)k * D_ + d] * C) / C;
    float n = 16384.0f;
    float denom = (ecs + 1e-5f) / (n + (float)K_ * 1e-5f) * n;
    out3[(size_t)k * D_ + d] = edw / denom;
}

extern "C" void kernel_launch(void* const* d_in, const int* in_sizes, int n_in,
                              void* d_out, int out_size, void* d_ws, size_t ws_size,
                              hipStream_t stream) {
    const float* x = (const float*)d_in[0];
    const float* E = (const float*)d_in[1];
    float* out = (float*)d_out;

    char* ws = (char*)d_ws;
    unsigned long long* best = (unsigned long long*)(ws);
    int*   cs  = (int*)  (ws + 131072);
    float* dw  = (float*)(ws + 163840);
    float* sse = (float*)(ws + 8552448);
    float* ssx = (float*)(ws + 8585216);

    __bf16* Xh = (__bf16*)out;
    __bf16* Xl = Xh + (size_t)N_ * D_;
    __bf16* Eh = (__bf16*)(out + 2 * (size_t)N_ * D_);
    __bf16* El = Eh + (size_t)K_ * D_;

    hipMemsetAsync(best, 0xFF, (size_t)N_ * 8, stream);
    // one memset covers cs + dw + sse + ssx (contiguous)
    hipMemsetAsync(cs, 0, 8650752 - 131072, stream);

    prep_e_kernel<<<K_ / 4, 256, 0, stream>>>(E, Eh, El, sse);
    prep_x_kernel<<<1024, 256, 0, stream>>>(x, Xh, Xl, ssx);
    dist_kernel<<<dim3(N_ / 128, K_ / 128), 256, 0, stream>>>(Eh, El, Xh, Xl, ssx, sse, best);
    scatter_kernel<<<256, 256, 0, stream>>>(x, E, best, out, cs, dw);
    finalize_kernel<<<K_, 256, 0, stream>>>(cs, dw, out + 3 * (size_t)N_ * D_);
}

// Round 5
// 266.095 us; speedup vs baseline: 4.0718x; 1.0321x over previous
//
#include <hip/hip_runtime.h>
#include <stdint.h>

#define B_ 8
#define D_ 256
#define T_ 2048
#define K_ 8192
#define N_ (B_*T_)   // 16384
#define NKT 12       // K=768 (3 products x 256) / BK=64

typedef __attribute__((ext_vector_type(8))) __bf16 bf16x8;
typedef __attribute__((ext_vector_type(4))) __bf16 bf16x4;
typedef __attribute__((ext_vector_type(2))) __bf16 bf16x2;
typedef __attribute__((ext_vector_type(4))) float f32x4;

// ---------------- workspace layout ----------------
// best: u64[N]   off 0         (131072 B)
// cs:   int[K]   off 131072    (32768 B)
// dw:   f32[K*D] off 163840    (8388608 B)
// sse:  f32[K]   off 8552448   (32768 B)
// ssx:  f32[N]   off 8585216   (65536 B)
// Interleaved GEMM panels live in d_out (scratch until scatter runs):
//   X2 = [12][16384][64] bf16 (25.2 MB) at out+0
//   E2 = [12][8192][64]  bf16 (12.6 MB) at out+32MB (out2 region)
// A2 = E2 = [El | Eh | Eh] over ktiles 0-3 | 4-7 | 8-11
// B2 = X2 = [Xh | Xl | Xh]  ->  dot = El.Xh + Eh.Xl + Eh.Xh  (3-product fp32 emu)

// split E -> interleaved bf16 panels AND sse row sums (fused)
__global__ __launch_bounds__(256) void prep_e_kernel(const float* __restrict__ E,
                                                     __bf16* __restrict__ E2,
                                                     float* __restrict__ sse) {
    int row  = blockIdx.x * 4 + (threadIdx.x >> 6);
    int lane = threadIdx.x & 63;
    float4 v = *(const float4*)(E + (size_t)row * D_ + lane * 4);
    __bf16 h0 = (__bf16)v.x, h1 = (__bf16)v.y, h2 = (__bf16)v.z, h3 = (__bf16)v.w;
    __bf16 l0 = (__bf16)(v.x - (float)h0), l1 = (__bf16)(v.y - (float)h1);
    __bf16 l2 = (__bf16)(v.z - (float)h2), l3 = (__bf16)(v.w - (float)h3);
    bf16x4 hv = {h0, h1, h2, h3};
    bf16x4 lv = {l0, l1, l2, l3};
    int p0  = lane >> 4;            // (d>>6), d = lane*4
    int col = (lane & 15) * 4;      // d & 63
    *(bf16x4*)(E2 + ((size_t)(p0    ) * K_ + row) * 64 + col) = lv;  // El
    *(bf16x4*)(E2 + ((size_t)(p0 + 4) * K_ + row) * 64 + col) = hv;  // Eh
    *(bf16x4*)(E2 + ((size_t)(p0 + 8) * K_ + row) * 64 + col) = hv;  // Eh
    float s = __fadd_rn(__fadd_rn(__fmul_rn(v.x, v.x), __fmul_rn(v.y, v.y)),
                        __fadd_rn(__fmul_rn(v.z, v.z), __fmul_rn(v.w, v.w)));
    #pragma unroll
    for (int off = 32; off > 0; off >>= 1) s += __shfl_down(s, off);
    if (lane == 0) sse[row] = s;
}

// transpose+split x -> interleaved bf16 panels AND accumulate ssx (fused)
__global__ __launch_bounds__(256) void prep_x_kernel(const float* __restrict__ x,
                                                     __bf16* __restrict__ X2,
                                                     float* __restrict__ ssx) {
    __shared__ float tile[64][65];
    __shared__ float part[64][4];
    int bidx = blockIdx.x;            // b(8) x dblk(4) x tblk(32)
    int b    = bidx >> 7;
    int dblk = (bidx >> 5) & 3;
    int tblk = bidx & 31;
    int d0 = dblk * 64, t0 = tblk * 64;
    const float* xp = x + (size_t)b * D_ * T_;
    {
        int tl = threadIdx.x & 63, th = threadIdx.x >> 6;
        float s = 0.f;
        #pragma unroll
        for (int i = 0; i < 16; i++) {
            int d = i * 4 + th;
            float v = xp[(size_t)(d0 + d) * T_ + t0 + tl];
            tile[d][tl] = v;
            s = __fadd_rn(s, __fmul_rn(v, v));
        }
        part[tl][th] = s;
    }
    __syncthreads();
    if (threadIdx.x < 64) {
        float tot = __fadd_rn(__fadd_rn(__fadd_rn(part[threadIdx.x][0],
                    part[threadIdx.x][1]), part[threadIdx.x][2]), part[threadIdx.x][3]);
        atomicAdd(ssx + b * T_ + t0 + threadIdx.x, tot);
    }
    {
        int dp = (threadIdx.x & 31) * 2, th = threadIdx.x >> 5;
        #pragma unroll
        for (int i = 0; i < 8; i++) {
            int t = i * 8 + th;
            float v0 = tile[dp][t], v1 = tile[dp + 1][t];
            __bf16 h0 = (__bf16)v0, h1 = (__bf16)v1;
            __bf16 q0 = (__bf16)(v0 - (float)h0), q1 = (__bf16)(v1 - (float)h1);
            size_t n = (size_t)b * T_ + t0 + t;
            bf16x2 hv = {h0, h1};
            bf16x2 lv = {q0, q1};
            // FIX (R4 bug): panels must be [Xh | Xl | Xh] to pair with [El | Eh | Eh]
            *(bf16x2*)(X2 + ((size_t)(dblk    ) * N_ + n) * 64 + dp) = hv;  // Xh
            *(bf16x2*)(X2 + ((size_t)(dblk + 4) * N_ + n) * 64 + dp) = lv;  // Xl
            *(bf16x2*)(X2 + ((size_t)(dblk + 8) * N_ + n) * 64 + dp) = hv;  // Xh
        }
    }
}

// -------- 256x256 8-phase MFMA distance + argmin --------
// A = codes (E2), B = x-rows (X2). 512 threads = 8 waves (2M x 4N).
// LDS: LA[2buf][2half][128x64] + LB same = 128 KiB, XOR-swizzled chunks.

#define STAGE_A(kt, half, buf) do {                                             \
    const char* gp_ = (const char*)A2 + ((size_t)(kt) * K_ + c0 + (half) * 128) * 128; \
    __bf16* lp_ = smem + ((buf) * 2 + (half)) * 8192;                           \
    __builtin_amdgcn_global_load_lds((const __attribute__((address_space(1))) void*)(gp_ + s1), \
        (__attribute__((address_space(3))) void*)(lp_ + wb1), 16, 0, 0);        \
    __builtin_amdgcn_global_load_lds((const __attribute__((address_space(1))) void*)(gp_ + s1 + 8192), \
        (__attribute__((address_space(3))) void*)(lp_ + wb2), 16, 0, 0);        \
  } while (0)

#define STAGE_B(kt, half, buf) do {                                             \
    const char* gp_ = (const char*)B2 + ((size_t)(kt) * N_ + r0 + (half) * 128) * 128; \
    __bf16* lp_ = smem + 32768 + ((buf) * 2 + (half)) * 8192;                   \
    __builtin_amdgcn_global_load_lds((const __attribute__((address_space(1))) void*)(gp_ + s1), \
        (__attribute__((address_space(3))) void*)(lp_ + wb1), 16, 0, 0);        \
    __builtin_amdgcn_global_load_lds((const __attribute__((address_space(1))) void*)(gp_ + s1 + 8192), \
        (__attribute__((address_space(3))) void*)(lp_ + wb2), 16, 0, 0);        \
  } while (0)

#define VMW(N) do { asm volatile("s_waitcnt vmcnt(" #N ")" ::: "memory");       \
                    __builtin_amdgcn_sched_barrier(0); } while (0)
#define NOPW ((void)0)

#define PHASE(bufi, h, g, STAGE_STMT, WAIT_STMT) do {                           \
    const __bf16* pa_ = smem + ((bufi) * 2 + (h)) * 8192;                       \
    const __bf16* pb_ = smem + 32768 + ((bufi) * 2 + (g)) * 8192;               \
    bf16x8 af_[2][4], bf_[2][2];                                                \
    _Pragma("unroll")                                                           \
    for (int kk = 0; kk < 2; kk++) {                                            \
      _Pragma("unroll")                                                         \
      for (int i = 0; i < 4; i++) {                                             \
        int row_ = wm * 64 + i * 16 + (l & 15);                                 \
        int byt_ = (row_ * 128 + (kk * 4 + (l >> 4)) * 16) ^ ((row_ & 7) << 4); \
        af_[kk][i] = *(const bf16x8*)((const char*)pa_ + byt_);                 \
      }                                                                         \
      _Pragma("unroll")                                                         \
      for (int j = 0; j < 2; j++) {                                             \
        int row_ = wn * 32 + j * 16 + (l & 15);                                 \
        int byt_ = (row_ * 128 + (kk * 4 + (l >> 4)) * 16) ^ ((row_ & 7) << 4); \
        bf_[kk][j] = *(const bf16x8*)((const char*)pb_ + byt_);                 \
      }                                                                         \
    }                                                                           \
    STAGE_STMT;                                                                 \
    __builtin_amdgcn_s_barrier();                                               \
    asm volatile("s_waitcnt lgkmcnt(0)" ::: "memory");                          \
    __builtin_amdgcn_sched_barrier(0);                                          \
    __builtin_amdgcn_s_setprio(1);                                              \
    _Pragma("unroll")                                                           \
    for (int kk = 0; kk < 2; kk++)                                              \
      _Pragma("unroll")                                                         \
      for (int i = 0; i < 4; i++)                                               \
        _Pragma("unroll")                                                       \
        for (int j = 0; j < 2; j++)                                             \
          acc[(h) * 4 + i][(g) * 2 + j] = __builtin_amdgcn_mfma_f32_16x16x32_bf16( \
              af_[kk][i], bf_[kk][j], acc[(h) * 4 + i][(g) * 2 + j], 0, 0, 0);  \
    __builtin_amdgcn_s_setprio(0);                                              \
    WAIT_STMT;                                                                  \
    __builtin_amdgcn_s_barrier();                                               \
    __builtin_amdgcn_sched_barrier(0);                                          \
  } while (0)

__global__ __launch_bounds__(512, 2) void dist_kernel(
    const __bf16* __restrict__ A2, const __bf16* __restrict__ B2,
    const float* __restrict__ ssx, const float* __restrict__ sse,
    unsigned long long* __restrict__ best)
{
    extern __shared__ __bf16 smem[];   // 65536 bf16 = 128 KiB

    const int tid = threadIdx.x;
    const int l   = tid & 63;
    const int w   = tid >> 6;        // 0..7
    const int wm  = w >> 2;          // M half within A-half (64 rows)
    const int wn  = w & 3;           // N quarter (32 cols)

    // XCD-aware swizzle; by-fastest so 32 consecutive blocks share an X2 panel
    const int bid = blockIdx.x;                  // 0..2047 (nwg % 8 == 0)
    const int swz = (bid & 7) * 256 + (bid >> 3);
    const int r0  = (swz >> 5) * 256;            // x-row tile
    const int c0  = (swz & 31) * 256;            // code tile

    // staging addressing: linear LDS dest, inverse-swizzled global source
    const int o1  = tid * 16;
    const int s1  = o1 ^ (((tid >> 3) & 7) << 4);   // involution on 16B chunks
    const int wb1 = w * 512;                         // elements
    const int wb2 = w * 512 + 4096;

    f32x4 acc[8][4];
    #pragma unroll
    for (int i = 0; i < 8; i++)
        #pragma unroll
        for (int j = 0; j < 4; j++) acc[i][j] = (f32x4)0.f;

    // prologue: tiles 0 (full) + 1 (halves 0) staged; wait first 2 half-pairs
    STAGE_A(0, 0, 0); STAGE_B(0, 0, 0);
    STAGE_A(0, 1, 0); STAGE_B(0, 1, 0);
    STAGE_A(1, 0, 1); STAGE_B(1, 0, 1);
    VMW(8);
    __builtin_amdgcn_s_barrier();
    __builtin_amdgcn_sched_barrier(0);

    #pragma unroll 1
    for (int it = 0; it < 5; it++) {
        const int tX = 2 * it;       // buf0; tY = tX+1 buf1
        PHASE(0, 0, 0, STAGE_A(tX + 1, 1, 1), VMW(6));
        PHASE(0, 0, 1, STAGE_B(tX + 1, 1, 1), NOPW);
        PHASE(0, 1, 0, STAGE_A(tX + 2, 0, 0), NOPW);
        PHASE(0, 1, 1, STAGE_B(tX + 2, 0, 0), VMW(8));
        PHASE(1, 0, 0, STAGE_A(tX + 2, 1, 0), VMW(6));
        PHASE(1, 0, 1, STAGE_B(tX + 2, 1, 0), NOPW);
        PHASE(1, 1, 0, STAGE_A(tX + 3, 0, 1), NOPW);
        PHASE(1, 1, 1, STAGE_B(tX + 3, 0, 1), VMW(8));
    }
    // peeled tail: tile 10 (buf0), tile 11 (buf1) with drain 6->4->0
    PHASE(0, 0, 0, STAGE_A(11, 1, 1), VMW(6));
    PHASE(0, 0, 1, STAGE_B(11, 1, 1), NOPW);
    PHASE(0, 1, 0, NOPW, NOPW);
    PHASE(0, 1, 1, NOPW, VMW(4));
    PHASE(1, 0, 0, NOPW, VMW(0));
    PHASE(1, 0, 1, NOPW, NOPW);
    PHASE(1, 1, 0, NOPW, NOPW);
    PHASE(1, 1, 1, NOPW, NOPW);

    // epilogue: dist = (ssx + sse) - 2*dot, packed-u64 argmin (ties -> low idx)
    #pragma unroll
    for (int g = 0; g < 2; g++) {
        #pragma unroll
        for (int j = 0; j < 2; j++) {
            int xrow = r0 + g * 128 + wn * 32 + j * 16 + (l & 15);
            float sx = ssx[xrow];
            unsigned long long m = ~0ull;
            #pragma unroll
            for (int h = 0; h < 2; h++) {
                #pragma unroll
                for (int i = 0; i < 4; i++) {
                    int cbase = c0 + h * 128 + wm * 64 + i * 16 + (l >> 4) * 4;
                    float4 sc = *(const float4*)(sse + cbase);
                    f32x4 a = acc[h * 4 + i][g * 2 + j];
                    float d0 = (sx + sc.x) - 2.0f * a[0];
                    float d1 = (sx + sc.y) - 2.0f * a[1];
                    float d2 = (sx + sc.z) - 2.0f * a[2];
                    float d3 = (sx + sc.w) - 2.0f * a[3];
                    unsigned long long p;
                    p = ((unsigned long long)__float_as_uint(d0) << 32) | (unsigned)(cbase + 0);
                    if (p < m) m = p;
                    p = ((unsigned long long)__float_as_uint(d1) << 32) | (unsigned)(cbase + 1);
                    if (p < m) m = p;
                    p = ((unsigned long long)__float_as_uint(d2) << 32) | (unsigned)(cbase + 2);
                    if (p < m) m = p;
                    p = ((unsigned long long)__float_as_uint(d3) << 32) | (unsigned)(cbase + 3);
                    if (p < m) m = p;
                }
            }
            unsigned long long o;
            o = __shfl_xor(m, 16); if (o < m) m = o;
            o = __shfl_xor(m, 32); if (o < m) m = o;
            if ((l >> 4) == 0) atomicMin(best + xrow, m);
        }
    }
}

// tiled coalesced gather/copy/stats: block = 64 n's x 256 d's
__global__ __launch_bounds__(256) void scatter_kernel(
    const float* __restrict__ x, const float* __restrict__ E,
    const unsigned long long* __restrict__ best,
    float* __restrict__ out, int* __restrict__ cs, float* __restrict__ dw)
{
    __shared__ float tx[64][68];
    __shared__ float te[64][68];
    __shared__ int sidx[64];

    const int blk = blockIdx.x;
    const int b   = blk >> 5;
    const int t0  = (blk & 31) * 64;
    const int tid = threadIdx.x;
    const int n0  = b * T_ + t0;

    if (tid < 64) {
        int ix = (int)(best[n0 + tid] & 0xffffffffu);
        sidx[tid] = ix;
        atomicAdd(cs + ix, 1);
    }
    __syncthreads();

    const int t4   = (tid & 15) * 4;
    const int dg   = tid >> 4;
    const int l    = tid & 63;
    const int w    = tid >> 6;
    const int nsub = l >> 4;
    const int dl4  = (l & 15) * 4;

    float* o0 = out;
    float* o1 = out + (size_t)N_ * D_;
    float* o2 = out + 2 * (size_t)N_ * D_;

    for (int dc = 0; dc < 4; dc++) {
        const int d0 = dc * 64;
        #pragma unroll
        for (int r = 0; r < 4; r++) {
            int d = r * 16 + dg;
            size_t gi = ((size_t)(b * D_ + d0 + d)) * T_ + t0 + t4;
            float4 v = *(const float4*)(x + gi);
            *(float4*)&tx[d][t4] = v;
            *(float4*)(o1 + gi) = v;
        }
        #pragma unroll
        for (int i = 0; i < 4; i++) {
            int nl  = w * 16 + i * 4 + nsub;
            int row = sidx[nl];
            float4 ev = *(const float4*)(E + (size_t)row * D_ + d0 + dl4);
            te[dl4 + 0][nl] = ev.x;
            te[dl4 + 1][nl] = ev.y;
            te[dl4 + 2][nl] = ev.z;
            te[dl4 + 3][nl] = ev.w;
        }
        __syncthreads();
        #pragma unroll
        for (int r = 0; r < 4; r++) {
            int d = r * 16 + dg;
            float4 v = *(const float4*)&te[d][t4];
            size_t gi = ((size_t)(b * D_ + d0 + d)) * T_ + t0 + t4;
            *(float4*)(o0 + gi) = v;
            *(float4*)(o2 + gi) = v;
        }
        #pragma unroll
        for (int i = 0; i < 16; i++) {
            int nl = w * 16 + i;
            atomicAdd(dw + (size_t)sidx[nl] * D_ + d0 + l, tx[l][nl]);
        }
        __syncthreads();
    }
}

__global__ __launch_bounds__(256) void finalize_kernel(
    const int* __restrict__ cs, const float* __restrict__ dw,
    float* __restrict__ out3)
{
    int k = blockIdx.x;
    int d = threadIdx.x;
    const float C = 0.00999999977648258209228515625f;
    float c   = (float)cs[k];
    float ecs = (c * C) / C;
    float edw = (dw[(size_t)k * D_ + d] * C) / C;
    float n = 16384.0f;
    float denom = (ecs + 1e-5f) / (n + (float)K_ * 1e-5f) * n;
    out3[(size_t)k * D_ + d] = edw / denom;
}

extern "C" void kernel_launch(void* const* d_in, const int* in_sizes, int n_in,
                              void* d_out, int out_size, void* d_ws, size_t ws_size,
                              hipStream_t stream) {
    const float* x = (const float*)d_in[0];
    const float* E = (const float*)d_in[1];
    float* out = (float*)d_out;

    char* ws = (char*)d_ws;
    unsigned long long* best = (unsigned long long*)(ws);
    int*   cs  = (int*)  (ws + 131072);
    float* dw  = (float*)(ws + 163840);
    float* sse = (float*)(ws + 8552448);
    float* ssx = (float*)(ws + 8585216);

    // interleaved panels in d_out scratch: X2 at 0 (25.2MB), E2 at +32MB (12.6MB)
    __bf16* X2 = (__bf16*)out;
    __bf16* E2 = (__bf16*)(out + 2 * (size_t)N_ * D_);

    hipMemsetAsync(best, 0xFF, (size_t)N_ * 8, stream);
    hipMemsetAsync(cs, 0, 8650752 - 131072, stream);   // cs+dw+sse+ssx contiguous

    hipFuncSetAttribute((const void*)dist_kernel,
                        hipFuncAttributeMaxDynamicSharedMemorySize, 131072);

    prep_e_kernel<<<K_ / 4, 256, 0, stream>>>(E, E2, sse);
    prep_x_kernel<<<1024, 256, 0, stream>>>(x, X2, ssx);
    dist_kernel<<<2048, 512, 131072, stream>>>(E2, X2, ssx, sse, best);
    scatter_kernel<<<256, 256, 0, stream>>>(x, E, best, out, cs, dw);
    finalize_kernel<<<K_, 256, 0, stream>>>(cs, dw, out + 3 * (size_t)N_ * D_);
}

// Round 6
// 250.974 us; speedup vs baseline: 4.3171x; 1.0603x over previous
//
#include <hip/hip_runtime.h>
#include <stdint.h>

#define B_ 8
#define D_ 256
#define T_ 2048
#define K_ 8192
#define N_ (B_*T_)   // 16384

typedef __attribute__((ext_vector_type(8))) __bf16 bf16x8;
typedef __attribute__((ext_vector_type(4))) __bf16 bf16x4;
typedef __attribute__((ext_vector_type(2))) __bf16 bf16x2;
typedef __attribute__((ext_vector_type(4))) float f32x4;

// ---------------- workspace layout ----------------
// best: u64[N]   off 0         (131072 B)
// cs:   int[K]   off 131072    (32768 B)
// dw:   f32[K*D] off 163840    (8388608 B)
// sse:  f32[K]   off 8552448   (32768 B)
// ssx:  f32[N]   off 8585216   (65536 B)
// Deduped GEMM panels in d_out (scratch until scatter runs):
//   X2 = [8][16384][64] bf16 (16.78 MB, exactly out0 region) at out+0
//        panels 0-3 = Xh, 4-7 = Xl
//   E2 = [8][8192][64]  bf16 (8.39 MB) at out+32MB (out2 region)
//        panels 0-3 = El, 4-7 = Eh
// k-tile t (0..11) maps: A panel = t>=8 ? t-4 : t   ([El|Eh|Eh])
//                        B panel = t & 7            ([Xh|Xl|Xh])
// -> dot = El.Xh + Eh.Xl + Eh.Xh (same product & accumulation order as R5)

// split E -> deduped bf16 panels AND sse row sums (fused)
__global__ __launch_bounds__(256) void prep_e_kernel(const float* __restrict__ E,
                                                     __bf16* __restrict__ E2,
                                                     float* __restrict__ sse) {
    int row  = blockIdx.x * 4 + (threadIdx.x >> 6);
    int lane = threadIdx.x & 63;
    float4 v = *(const float4*)(E + (size_t)row * D_ + lane * 4);
    __bf16 h0 = (__bf16)v.x, h1 = (__bf16)v.y, h2 = (__bf16)v.z, h3 = (__bf16)v.w;
    __bf16 l0 = (__bf16)(v.x - (float)h0), l1 = (__bf16)(v.y - (float)h1);
    __bf16 l2 = (__bf16)(v.z - (float)h2), l3 = (__bf16)(v.w - (float)h3);
    bf16x4 hv = {h0, h1, h2, h3};
    bf16x4 lv = {l0, l1, l2, l3};
    int p0  = lane >> 4;            // (d>>6), d = lane*4
    int col = (lane & 15) * 4;      // d & 63
    *(bf16x4*)(E2 + ((size_t)(p0    ) * K_ + row) * 64 + col) = lv;  // El
    *(bf16x4*)(E2 + ((size_t)(p0 + 4) * K_ + row) * 64 + col) = hv;  // Eh
    float s = __fadd_rn(__fadd_rn(__fmul_rn(v.x, v.x), __fmul_rn(v.y, v.y)),
                        __fadd_rn(__fmul_rn(v.z, v.z), __fmul_rn(v.w, v.w)));
    #pragma unroll
    for (int off = 32; off > 0; off >>= 1) s += __shfl_down(s, off);
    if (lane == 0) sse[row] = s;
}

// transpose+split x -> deduped bf16 panels AND accumulate ssx (fused)
__global__ __launch_bounds__(256) void prep_x_kernel(const float* __restrict__ x,
                                                     __bf16* __restrict__ X2,
                                                     float* __restrict__ ssx) {
    __shared__ float tile[64][65];
    __shared__ float part[64][4];
    int bidx = blockIdx.x;            // b(8) x dblk(4) x tblk(32)
    int b    = bidx >> 7;
    int dblk = (bidx >> 5) & 3;
    int tblk = bidx & 31;
    int d0 = dblk * 64, t0 = tblk * 64;
    const float* xp = x + (size_t)b * D_ * T_;
    {
        int tl = threadIdx.x & 63, th = threadIdx.x >> 6;
        float s = 0.f;
        #pragma unroll
        for (int i = 0; i < 16; i++) {
            int d = i * 4 + th;
            float v = xp[(size_t)(d0 + d) * T_ + t0 + tl];
            tile[d][tl] = v;
            s = __fadd_rn(s, __fmul_rn(v, v));
        }
        part[tl][th] = s;
    }
    __syncthreads();
    if (threadIdx.x < 64) {
        float tot = __fadd_rn(__fadd_rn(__fadd_rn(part[threadIdx.x][0],
                    part[threadIdx.x][1]), part[threadIdx.x][2]), part[threadIdx.x][3]);
        atomicAdd(ssx + b * T_ + t0 + threadIdx.x, tot);
    }
    {
        int dp = (threadIdx.x & 31) * 2, th = threadIdx.x >> 5;
        #pragma unroll
        for (int i = 0; i < 8; i++) {
            int t = i * 8 + th;
            float v0 = tile[dp][t], v1 = tile[dp + 1][t];
            __bf16 h0 = (__bf16)v0, h1 = (__bf16)v1;
            __bf16 q0 = (__bf16)(v0 - (float)h0), q1 = (__bf16)(v1 - (float)h1);
            size_t n = (size_t)b * T_ + t0 + t;
            bf16x2 hv = {h0, h1};
            bf16x2 lv = {q0, q1};
            *(bf16x2*)(X2 + ((size_t)(dblk    ) * N_ + n) * 64 + dp) = hv;  // Xh
            *(bf16x2*)(X2 + ((size_t)(dblk + 4) * N_ + n) * 64 + dp) = lv;  // Xl
        }
    }
}

// -------- 256x256 8-phase MFMA distance + argmin --------
// A = codes (E2), B = x-rows (X2). 512 threads = 8 waves (2M x 4N).
// LDS: LA[2buf][2half][128x64] + LB same = 128 KiB, XOR-swizzled chunks.

#define STAGE_A(kt, half, buf) do {                                             \
    const int pkt_ = ((kt) >= 8) ? (kt) - 4 : (kt);                             \
    const char* gp_ = (const char*)A2 + ((size_t)pkt_ * K_ + c0 + (half) * 128) * 128; \
    __bf16* lp_ = smem + ((buf) * 2 + (half)) * 8192;                           \
    __builtin_amdgcn_global_load_lds((const __attribute__((address_space(1))) void*)(gp_ + s1), \
        (__attribute__((address_space(3))) void*)(lp_ + wb1), 16, 0, 0);        \
    __builtin_amdgcn_global_load_lds((const __attribute__((address_space(1))) void*)(gp_ + s1 + 8192), \
        (__attribute__((address_space(3))) void*)(lp_ + wb2), 16, 0, 0);        \
  } while (0)

#define STAGE_B(kt, half, buf) do {                                             \
    const int pkt_ = (kt) & 7;                                                  \
    const char* gp_ = (const char*)B2 + ((size_t)pkt_ * N_ + r0 + (half) * 128) * 128; \
    __bf16* lp_ = smem + 32768 + ((buf) * 2 + (half)) * 8192;                   \
    __builtin_amdgcn_global_load_lds((const __attribute__((address_space(1))) void*)(gp_ + s1), \
        (__attribute__((address_space(3))) void*)(lp_ + wb1), 16, 0, 0);        \
    __builtin_amdgcn_global_load_lds((const __attribute__((address_space(1))) void*)(gp_ + s1 + 8192), \
        (__attribute__((address_space(3))) void*)(lp_ + wb2), 16, 0, 0);        \
  } while (0)

#define VMW(N) do { asm volatile("s_waitcnt vmcnt(" #N ")" ::: "memory");       \
                    __builtin_amdgcn_sched_barrier(0); } while (0)
#define NOPW ((void)0)

#define PHASE(bufi, h, g, STAGE_STMT, WAIT_STMT) do {                           \
    const __bf16* pa_ = smem + ((bufi) * 2 + (h)) * 8192;                       \
    const __bf16* pb_ = smem + 32768 + ((bufi) * 2 + (g)) * 8192;               \
    bf16x8 af_[2][4], bf_[2][2];                                                \
    _Pragma("unroll")                                                           \
    for (int kk = 0; kk < 2; kk++) {                                            \
      _Pragma("unroll")                                                         \
      for (int i = 0; i < 4; i++) {                                             \
        int row_ = wm * 64 + i * 16 + (l & 15);                                 \
        int byt_ = (row_ * 128 + (kk * 4 + (l >> 4)) * 16) ^ ((row_ & 7) << 4); \
        af_[kk][i] = *(const bf16x8*)((const char*)pa_ + byt_);                 \
      }                                                                         \
      _Pragma("unroll")                                                         \
      for (int j = 0; j < 2; j++) {                                             \
        int row_ = wn * 32 + j * 16 + (l & 15);                                 \
        int byt_ = (row_ * 128 + (kk * 4 + (l >> 4)) * 16) ^ ((row_ & 7) << 4); \
        bf_[kk][j] = *(const bf16x8*)((const char*)pb_ + byt_);                 \
      }                                                                         \
    }                                                                           \
    STAGE_STMT;                                                                 \
    __builtin_amdgcn_s_barrier();                                               \
    asm volatile("s_waitcnt lgkmcnt(0)" ::: "memory");                          \
    __builtin_amdgcn_sched_barrier(0);                                          \
    __builtin_amdgcn_s_setprio(1);                                              \
    _Pragma("unroll")                                                           \
    for (int kk = 0; kk < 2; kk++)                                              \
      _Pragma("unroll")                                                         \
      for (int i = 0; i < 4; i++)                                               \
        _Pragma("unroll")                                                       \
        for (int j = 0; j < 2; j++)                                             \
          acc[(h) * 4 + i][(g) * 2 + j] = __builtin_amdgcn_mfma_f32_16x16x32_bf16( \
              af_[kk][i], bf_[kk][j], acc[(h) * 4 + i][(g) * 2 + j], 0, 0, 0);  \
    __builtin_amdgcn_s_setprio(0);                                              \
    WAIT_STMT;                                                                  \
    __builtin_amdgcn_s_barrier();                                               \
    __builtin_amdgcn_sched_barrier(0);                                          \
  } while (0)

__global__ __launch_bounds__(512, 2) void dist_kernel(
    const __bf16* __restrict__ A2, const __bf16* __restrict__ B2,
    const float* __restrict__ ssx, const float* __restrict__ sse,
    unsigned long long* __restrict__ best)
{
    extern __shared__ __bf16 smem[];   // 65536 bf16 = 128 KiB

    const int tid = threadIdx.x;
    const int l   = tid & 63;
    const int w   = tid >> 6;        // 0..7
    const int wm  = w >> 2;          // M half within A-half (64 rows)
    const int wn  = w & 3;           // N quarter (32 cols)

    // L2-resident XCD mapping: XCD x owns c-tiles [4x,4x+4) x all 64 r-tiles.
    // Within an XCD, c cycles fastest so the 4 A-panels (1 MB) stay L2-hot.
    const int bid = blockIdx.x;                  // 0..2047, xcd = bid & 7
    const int xq  = bid & 7;
    const int i_  = bid >> 3;                    // 0..255 per XCD
    const int c0  = (xq * 4 + (i_ & 3)) * 256;   // code tile
    const int r0  = (i_ >> 2) * 256;             // x-row tile

    // staging addressing: linear LDS dest, inverse-swizzled global source
    const int o1  = tid * 16;
    const int s1  = o1 ^ (((tid >> 3) & 7) << 4);   // involution on 16B chunks
    const int wb1 = w * 512;                         // elements
    const int wb2 = w * 512 + 4096;

    f32x4 acc[8][4];
    #pragma unroll
    for (int i = 0; i < 8; i++)
        #pragma unroll
        for (int j = 0; j < 4; j++) acc[i][j] = (f32x4)0.f;

    // prologue: tiles 0 (full) + 1 (halves 0) staged; wait first 2 half-pairs
    STAGE_A(0, 0, 0); STAGE_B(0, 0, 0);
    STAGE_A(0, 1, 0); STAGE_B(0, 1, 0);
    STAGE_A(1, 0, 1); STAGE_B(1, 0, 1);
    VMW(8);
    __builtin_amdgcn_s_barrier();
    __builtin_amdgcn_sched_barrier(0);

    #pragma unroll 1
    for (int it = 0; it < 5; it++) {
        const int tX = 2 * it;       // buf0; tY = tX+1 buf1
        PHASE(0, 0, 0, STAGE_A(tX + 1, 1, 1), VMW(6));
        PHASE(0, 0, 1, STAGE_B(tX + 1, 1, 1), NOPW);
        PHASE(0, 1, 0, STAGE_A(tX + 2, 0, 0), NOPW);
        PHASE(0, 1, 1, STAGE_B(tX + 2, 0, 0), VMW(8));
        PHASE(1, 0, 0, STAGE_A(tX + 2, 1, 0), VMW(6));
        PHASE(1, 0, 1, STAGE_B(tX + 2, 1, 0), NOPW);
        PHASE(1, 1, 0, STAGE_A(tX + 3, 0, 1), NOPW);
        PHASE(1, 1, 1, STAGE_B(tX + 3, 0, 1), VMW(8));
    }
    // peeled tail: tile 10 (buf0), tile 11 (buf1) with drain 6->4->0
    PHASE(0, 0, 0, STAGE_A(11, 1, 1), VMW(6));
    PHASE(0, 0, 1, STAGE_B(11, 1, 1), NOPW);
    PHASE(0, 1, 0, NOPW, NOPW);
    PHASE(0, 1, 1, NOPW, VMW(4));
    PHASE(1, 0, 0, NOPW, VMW(0));
    PHASE(1, 0, 1, NOPW, NOPW);
    PHASE(1, 1, 0, NOPW, NOPW);
    PHASE(1, 1, 1, NOPW, NOPW);

    // epilogue: dist = (ssx + sse) - 2*dot, packed-u64 argmin (ties -> low idx)
    #pragma unroll
    for (int g = 0; g < 2; g++) {
        #pragma unroll
        for (int j = 0; j < 2; j++) {
            int xrow = r0 + g * 128 + wn * 32 + j * 16 + (l & 15);
            float sx = ssx[xrow];
            unsigned long long m = ~0ull;
            #pragma unroll
            for (int h = 0; h < 2; h++) {
                #pragma unroll
                for (int i = 0; i < 4; i++) {
                    int cbase = c0 + h * 128 + wm * 64 + i * 16 + (l >> 4) * 4;
                    float4 sc = *(const float4*)(sse + cbase);
                    f32x4 a = acc[h * 4 + i][g * 2 + j];
                    float d0 = (sx + sc.x) - 2.0f * a[0];
                    float d1 = (sx + sc.y) - 2.0f * a[1];
                    float d2 = (sx + sc.z) - 2.0f * a[2];
                    float d3 = (sx + sc.w) - 2.0f * a[3];
                    unsigned long long p;
                    p = ((unsigned long long)__float_as_uint(d0) << 32) | (unsigned)(cbase + 0);
                    if (p < m) m = p;
                    p = ((unsigned long long)__float_as_uint(d1) << 32) | (unsigned)(cbase + 1);
                    if (p < m) m = p;
                    p = ((unsigned long long)__float_as_uint(d2) << 32) | (unsigned)(cbase + 2);
                    if (p < m) m = p;
                    p = ((unsigned long long)__float_as_uint(d3) << 32) | (unsigned)(cbase + 3);
                    if (p < m) m = p;
                }
            }
            unsigned long long o;
            o = __shfl_xor(m, 16); if (o < m) m = o;
            o = __shfl_xor(m, 32); if (o < m) m = o;
            if ((l >> 4) == 0) atomicMin(best + xrow, m);
        }
    }
}

// tiled coalesced gather/copy/stats: block = 64 n's x 256 d's
__global__ __launch_bounds__(256) void scatter_kernel(
    const float* __restrict__ x, const float* __restrict__ E,
    const unsigned long long* __restrict__ best,
    float* __restrict__ out, int* __restrict__ cs, float* __restrict__ dw)
{
    __shared__ float tx[64][68];
    __shared__ float te[64][68];
    __shared__ int sidx[64];

    const int blk = blockIdx.x;
    const int b   = blk >> 5;
    const int t0  = (blk & 31) * 64;
    const int tid = threadIdx.x;
    const int n0  = b * T_ + t0;

    if (tid < 64) {
        int ix = (int)(best[n0 + tid] & 0xffffffffu);
        sidx[tid] = ix;
        atomicAdd(cs + ix, 1);
    }
    __syncthreads();

    const int t4   = (tid & 15) * 4;
    const int dg   = tid >> 4;
    const int l    = tid & 63;
    const int w    = tid >> 6;
    const int nsub = l >> 4;
    const int dl4  = (l & 15) * 4;

    float* o0 = out;
    float* o1 = out + (size_t)N_ * D_;
    float* o2 = out + 2 * (size_t)N_ * D_;

    for (int dc = 0; dc < 4; dc++) {
        const int d0 = dc * 64;
        #pragma unroll
        for (int r = 0; r < 4; r++) {
            int d = r * 16 + dg;
            size_t gi = ((size_t)(b * D_ + d0 + d)) * T_ + t0 + t4;
            float4 v = *(const float4*)(x + gi);
            *(float4*)&tx[d][t4] = v;
            *(float4*)(o1 + gi) = v;
        }
        #pragma unroll
        for (int i = 0; i < 4; i++) {
            int nl  = w * 16 + i * 4 + nsub;
            int row = sidx[nl];
            float4 ev = *(const float4*)(E + (size_t)row * D_ + d0 + dl4);
            te[dl4 + 0][nl] = ev.x;
            te[dl4 + 1][nl] = ev.y;
            te[dl4 + 2][nl] = ev.z;
            te[dl4 + 3][nl] = ev.w;
        }
        __syncthreads();
        #pragma unroll
        for (int r = 0; r < 4; r++) {
            int d = r * 16 + dg;
            float4 v = *(const float4*)&te[d][t4];
            size_t gi = ((size_t)(b * D_ + d0 + d)) * T_ + t0 + t4;
            *(float4*)(o0 + gi) = v;
            *(float4*)(o2 + gi) = v;
        }
        #pragma unroll
        for (int i = 0; i < 16; i++) {
            int nl = w * 16 + i;
            atomicAdd(dw + (size_t)sidx[nl] * D_ + d0 + l, tx[l][nl]);
        }
        __syncthreads();
    }
}

__global__ __launch_bounds__(256) void finalize_kernel(
    const int* __restrict__ cs, const float* __restrict__ dw,
    float* __restrict__ out3)
{
    int k = blockIdx.x;
    int d = threadIdx.x;
    const float C = 0.00999999977648258209228515625f;
    float c   = (float)cs[k];
    float ecs = (c * C) / C;
    float edw = (dw[(size_t)k * D_ + d] * C) / C;
    float n = 16384.0f;
    float denom = (ecs + 1e-5f) / (n + (float)K_ * 1e-5f) * n;
    out3[(size_t)k * D_ + d] = edw / denom;
}

extern "C" void kernel_launch(void* const* d_in, const int* in_sizes, int n_in,
                              void* d_out, int out_size, void* d_ws, size_t ws_size,
                              hipStream_t stream) {
    const float* x = (const float*)d_in[0];
    const float* E = (const float*)d_in[1];
    float* out = (float*)d_out;

    char* ws = (char*)d_ws;
    unsigned long long* best = (unsigned long long*)(ws);
    int*   cs  = (int*)  (ws + 131072);
    float* dw  = (float*)(ws + 163840);
    float* sse = (float*)(ws + 8552448);
    float* ssx = (float*)(ws + 8585216);

    // deduped panels in d_out scratch: X2 (16.78 MB, fits out0 exactly),
    // E2 (8.39 MB) in out2 region
    __bf16* X2 = (__bf16*)out;
    __bf16* E2 = (__bf16*)(out + 2 * (size_t)N_ * D_);

    hipMemsetAsync(best, 0xFF, (size_t)N_ * 8, stream);
    hipMemsetAsync(cs, 0, 8650752 - 131072, stream);   // cs+dw+sse+ssx contiguous

    hipFuncSetAttribute((const void*)dist_kernel,
                        hipFuncAttributeMaxDynamicSharedMemorySize, 131072);

    prep_e_kernel<<<K_ / 4, 256, 0, stream>>>(E, E2, sse);
    prep_x_kernel<<<1024, 256, 0, stream>>>(x, X2, ssx);
    dist_kernel<<<2048, 512, 131072, stream>>>(E2, X2, ssx, sse, best);
    scatter_kernel<<<256, 256, 0, stream>>>(x, E, best, out, cs, dw);
    finalize_kernel<<<K_, 256, 0, stream>>>(cs, dw, out + 3 * (size_t)N_ * D_);
}

// Round 7
// 229.315 us; speedup vs baseline: 4.7249x; 1.0944x over previous
//
#include <hip/hip_runtime.h>
#include <stdint.h>

#define B_ 8
#define D_ 256
#define T_ 2048
#define K_ 8192
#define N_ (B_*T_)   // 16384

typedef __attribute__((ext_vector_type(8))) __bf16 bf16x8;
typedef __attribute__((ext_vector_type(4))) __bf16 bf16x4;
typedef __attribute__((ext_vector_type(2))) __bf16 bf16x2;
typedef __attribute__((ext_vector_type(4))) float f32x4;

// ---------------- workspace layout ----------------
// best: u64[N]   off 0         (131072 B)
// cs:   int[K]   off 131072    (32768 B)
// dw:   f32[K*D] off 163840    (8388608 B)
// sse:  f32[K]   off 8552448   (32768 B)
// ssx:  f32[N]   off 8585216   (65536 B)
// Deduped GEMM panels in d_out (scratch until scatter runs):
//   X2 = [8][16384][64] bf16 (16.78 MB) at out+0      (panels 0-3 Xh, 4-7 Xl)
//   E2 = [8][8192][64]  bf16 (8.39 MB)  at out+32MB   (panels 0-3 El, 4-7 Eh)
// k-tile t (0..11): A panel = t>=8 ? t-4 : t ([El|Eh|Eh]); B panel = t&7 ([Xh|Xl|Xh])
// -> dot = El.Xh + Eh.Xl + Eh.Xh (identical products & per-acc order as R5/R6)

__global__ __launch_bounds__(256) void prep_e_kernel(const float* __restrict__ E,
                                                     __bf16* __restrict__ E2,
                                                     float* __restrict__ sse) {
    int row  = blockIdx.x * 4 + (threadIdx.x >> 6);
    int lane = threadIdx.x & 63;
    float4 v = *(const float4*)(E + (size_t)row * D_ + lane * 4);
    __bf16 h0 = (__bf16)v.x, h1 = (__bf16)v.y, h2 = (__bf16)v.z, h3 = (__bf16)v.w;
    __bf16 l0 = (__bf16)(v.x - (float)h0), l1 = (__bf16)(v.y - (float)h1);
    __bf16 l2 = (__bf16)(v.z - (float)h2), l3 = (__bf16)(v.w - (float)h3);
    bf16x4 hv = {h0, h1, h2, h3};
    bf16x4 lv = {l0, l1, l2, l3};
    int p0  = lane >> 4;
    int col = (lane & 15) * 4;
    *(bf16x4*)(E2 + ((size_t)(p0    ) * K_ + row) * 64 + col) = lv;  // El
    *(bf16x4*)(E2 + ((size_t)(p0 + 4) * K_ + row) * 64 + col) = hv;  // Eh
    float s = __fadd_rn(__fadd_rn(__fmul_rn(v.x, v.x), __fmul_rn(v.y, v.y)),
                        __fadd_rn(__fmul_rn(v.z, v.z), __fmul_rn(v.w, v.w)));
    #pragma unroll
    for (int off = 32; off > 0; off >>= 1) s += __shfl_down(s, off);
    if (lane == 0) sse[row] = s;
}

__global__ __launch_bounds__(256) void prep_x_kernel(const float* __restrict__ x,
                                                     __bf16* __restrict__ X2,
                                                     float* __restrict__ ssx) {
    __shared__ float tile[64][65];
    __shared__ float part[64][4];
    int bidx = blockIdx.x;            // b(8) x dblk(4) x tblk(32)
    int b    = bidx >> 7;
    int dblk = (bidx >> 5) & 3;
    int tblk = bidx & 31;
    int d0 = dblk * 64, t0 = tblk * 64;
    const float* xp = x + (size_t)b * D_ * T_;
    {
        int tl = threadIdx.x & 63, th = threadIdx.x >> 6;
        float s = 0.f;
        #pragma unroll
        for (int i = 0; i < 16; i++) {
            int d = i * 4 + th;
            float v = xp[(size_t)(d0 + d) * T_ + t0 + tl];
            tile[d][tl] = v;
            s = __fadd_rn(s, __fmul_rn(v, v));
        }
        part[tl][th] = s;
    }
    __syncthreads();
    if (threadIdx.x < 64) {
        float tot = __fadd_rn(__fadd_rn(__fadd_rn(part[threadIdx.x][0],
                    part[threadIdx.x][1]), part[threadIdx.x][2]), part[threadIdx.x][3]);
        atomicAdd(ssx + b * T_ + t0 + threadIdx.x, tot);
    }
    {
        int dp = (threadIdx.x & 31) * 2, th = threadIdx.x >> 5;
        #pragma unroll
        for (int i = 0; i < 8; i++) {
            int t = i * 8 + th;
            float v0 = tile[dp][t], v1 = tile[dp + 1][t];
            __bf16 h0 = (__bf16)v0, h1 = (__bf16)v1;
            __bf16 q0 = (__bf16)(v0 - (float)h0), q1 = (__bf16)(v1 - (float)h1);
            size_t n = (size_t)b * T_ + t0 + t;
            bf16x2 hv = {h0, h1};
            bf16x2 lv = {q0, q1};
            *(bf16x2*)(X2 + ((size_t)(dblk    ) * N_ + n) * 64 + dp) = hv;  // Xh
            *(bf16x2*)(X2 + ((size_t)(dblk + 4) * N_ + n) * 64 + dp) = lv;  // Xl
        }
    }
}

// -------- 256x256 8-phase MFMA distance + argmin --------
// Frag-minimal K-tile: quadrant order (0,0)->(0,1)->(1,1)->(1,0); A reloaded
// once (h=1), B0/B1 held in separate reg sets -> 24 ds_read_b128 per K-tile
// per wave (was 48). Barriers / STAGE slots / vmcnt ledger identical to R6.

#define STAGE_A(kt, half, buf) do {                                             \
    const int pkt_ = ((kt) >= 8) ? (kt) - 4 : (kt);                             \
    const char* gp_ = (const char*)A2 + ((size_t)pkt_ * K_ + c0 + (half) * 128) * 128; \
    __bf16* lp_ = smem + ((buf) * 2 + (half)) * 8192;                           \
    __builtin_amdgcn_global_load_lds((const __attribute__((address_space(1))) void*)(gp_ + s1), \
        (__attribute__((address_space(3))) void*)(lp_ + wb1), 16, 0, 0);        \
    __builtin_amdgcn_global_load_lds((const __attribute__((address_space(1))) void*)(gp_ + s1 + 8192), \
        (__attribute__((address_space(3))) void*)(lp_ + wb2), 16, 0, 0);        \
  } while (0)

#define STAGE_B(kt, half, buf) do {                                             \
    const int pkt_ = (kt) & 7;                                                  \
    const char* gp_ = (const char*)B2 + ((size_t)pkt_ * N_ + r0 + (half) * 128) * 128; \
    __bf16* lp_ = smem + 32768 + ((buf) * 2 + (half)) * 8192;                   \
    __builtin_amdgcn_global_load_lds((const __attribute__((address_space(1))) void*)(gp_ + s1), \
        (__attribute__((address_space(3))) void*)(lp_ + wb1), 16, 0, 0);        \
    __builtin_amdgcn_global_load_lds((const __attribute__((address_space(1))) void*)(gp_ + s1 + 8192), \
        (__attribute__((address_space(3))) void*)(lp_ + wb2), 16, 0, 0);        \
  } while (0)

#define VMW(N) do { asm volatile("s_waitcnt vmcnt(" #N ")" ::: "memory");       \
                    __builtin_amdgcn_sched_barrier(0); } while (0)
#define NOPW ((void)0)

#define LOAD_A(DST, PA)                                                          \
    _Pragma("unroll")                                                            \
    for (int kk = 0; kk < 2; kk++) {                                             \
      _Pragma("unroll")                                                          \
      for (int i = 0; i < 4; i++) {                                              \
        int row_ = wm * 64 + i * 16 + (l & 15);                                  \
        int byt_ = (row_ * 128 + (kk * 4 + (l >> 4)) * 16) ^ ((row_ & 7) << 4);  \
        DST[kk][i] = *(const bf16x8*)((const char*)(PA) + byt_);                 \
      }                                                                          \
    }

#define LOAD_B(DST, PB)                                                          \
    _Pragma("unroll")                                                            \
    for (int kk = 0; kk < 2; kk++) {                                             \
      _Pragma("unroll")                                                          \
      for (int j = 0; j < 2; j++) {                                              \
        int row_ = wn * 32 + j * 16 + (l & 15);                                  \
        int byt_ = (row_ * 128 + (kk * 4 + (l >> 4)) * 16) ^ ((row_ & 7) << 4);  \
        DST[kk][j] = *(const bf16x8*)((const char*)(PB) + byt_);                 \
      }                                                                          \
    }

#define MFMA16(H, G, AF, BF)                                                     \
    _Pragma("unroll")                                                            \
    for (int kk = 0; kk < 2; kk++)                                               \
      _Pragma("unroll")                                                          \
      for (int i = 0; i < 4; i++)                                                \
        _Pragma("unroll")                                                        \
        for (int j = 0; j < 2; j++)                                              \
          acc[(H) * 4 + i][(G) * 2 + j] = __builtin_amdgcn_mfma_f32_16x16x32_bf16( \
              AF[kk][i], BF[kk][j], acc[(H) * 4 + i][(G) * 2 + j], 0, 0, 0)

#define PHX(LOADS, STAGE_STMT, H, G, AF, BF, WAIT_STMT) do {                     \
    LOADS;                                                                       \
    STAGE_STMT;                                                                  \
    __builtin_amdgcn_s_barrier();                                                \
    asm volatile("s_waitcnt lgkmcnt(0)" ::: "memory");                           \
    __builtin_amdgcn_sched_barrier(0);                                           \
    __builtin_amdgcn_s_setprio(1);                                               \
    MFMA16(H, G, AF, BF);                                                        \
    __builtin_amdgcn_s_setprio(0);                                               \
    WAIT_STMT;                                                                   \
    __builtin_amdgcn_s_barrier();                                                \
    __builtin_amdgcn_sched_barrier(0);                                           \
  } while (0)

#define KTILE(bufi, S1, W1, S2, W2, S3, W3, S4, W4) do {                         \
    const __bf16* paL_ = smem + ((bufi) * 2 + 0) * 8192;                         \
    const __bf16* paH_ = smem + ((bufi) * 2 + 1) * 8192;                         \
    const __bf16* pbL_ = smem + 32768 + ((bufi) * 2 + 0) * 8192;                 \
    const __bf16* pbH_ = smem + 32768 + ((bufi) * 2 + 1) * 8192;                 \
    bf16x8 af_[2][4], b0_[2][2], b1_[2][2];                                      \
    PHX({ LOAD_A(af_, paL_); LOAD_B(b0_, pbL_); }, S1, 0, 0, af_, b0_, W1);      \
    PHX({ LOAD_B(b1_, pbH_); },                    S2, 0, 1, af_, b1_, W2);      \
    PHX({ LOAD_A(af_, paH_); },                    S3, 1, 1, af_, b1_, W3);      \
    PHX({ ; },                                     S4, 1, 0, af_, b0_, W4);      \
  } while (0)

__global__ __launch_bounds__(512, 2) void dist_kernel(
    const __bf16* __restrict__ A2, const __bf16* __restrict__ B2,
    const float* __restrict__ ssx, const float* __restrict__ sse,
    unsigned long long* __restrict__ best)
{
    extern __shared__ __bf16 smem[];   // 65536 bf16 = 128 KiB

    const int tid = threadIdx.x;
    const int l   = tid & 63;
    const int w   = tid >> 6;        // 0..7
    const int wm  = w >> 2;          // M half within A-half (64 rows)
    const int wn  = w & 3;           // N quarter (32 cols)

    // L2-resident XCD mapping: XCD x owns c-tiles [4x,4x+4) x all 64 r-tiles.
    const int bid = blockIdx.x;
    const int xq  = bid & 7;
    const int i_  = bid >> 3;
    const int c0  = (xq * 4 + (i_ & 3)) * 256;
    const int r0  = (i_ >> 2) * 256;

    // staging addressing: linear LDS dest, inverse-swizzled global source
    const int o1  = tid * 16;
    const int s1  = o1 ^ (((tid >> 3) & 7) << 4);
    const int wb1 = w * 512;
    const int wb2 = w * 512 + 4096;

    f32x4 acc[8][4];
    #pragma unroll
    for (int i = 0; i < 8; i++)
        #pragma unroll
        for (int j = 0; j < 4; j++) acc[i][j] = (f32x4)0.f;

    // prologue: tiles 0 (full) + 1 (halves 0) staged; wait first 2 half-pairs
    STAGE_A(0, 0, 0); STAGE_B(0, 0, 0);
    STAGE_A(0, 1, 0); STAGE_B(0, 1, 0);
    STAGE_A(1, 0, 1); STAGE_B(1, 0, 1);
    VMW(8);
    __builtin_amdgcn_s_barrier();
    __builtin_amdgcn_sched_barrier(0);

    #pragma unroll 1
    for (int it = 0; it < 5; it++) {
        const int tX = 2 * it;
        KTILE(0, STAGE_A(tX + 1, 1, 1), VMW(6),
                 STAGE_B(tX + 1, 1, 1), NOPW,
                 STAGE_A(tX + 2, 0, 0), NOPW,
                 STAGE_B(tX + 2, 0, 0), VMW(8));
        KTILE(1, STAGE_A(tX + 2, 1, 0), VMW(6),
                 STAGE_B(tX + 2, 1, 0), NOPW,
                 STAGE_A(tX + 3, 0, 1), NOPW,
                 STAGE_B(tX + 3, 0, 1), VMW(8));
    }
    // peeled tail: tile 10 (buf0), tile 11 (buf1), drain 6->4->0
    KTILE(0, STAGE_A(11, 1, 1), VMW(6),
             STAGE_B(11, 1, 1), NOPW,
             NOPW, NOPW,
             NOPW, VMW(4));
    KTILE(1, NOPW, VMW(0),
             NOPW, NOPW,
             NOPW, NOPW,
             NOPW, NOPW);

    // epilogue: dist = (ssx + sse) - 2*dot, packed-u64 argmin (ties -> low idx)
    #pragma unroll
    for (int g = 0; g < 2; g++) {
        #pragma unroll
        for (int j = 0; j < 2; j++) {
            int xrow = r0 + g * 128 + wn * 32 + j * 16 + (l & 15);
            float sx = ssx[xrow];
            unsigned long long m = ~0ull;
            #pragma unroll
            for (int h = 0; h < 2; h++) {
                #pragma unroll
                for (int i = 0; i < 4; i++) {
                    int cbase = c0 + h * 128 + wm * 64 + i * 16 + (l >> 4) * 4;
                    float4 sc = *(const float4*)(sse + cbase);
                    f32x4 a = acc[h * 4 + i][g * 2 + j];
                    float d0 = (sx + sc.x) - 2.0f * a[0];
                    float d1 = (sx + sc.y) - 2.0f * a[1];
                    float d2 = (sx + sc.z) - 2.0f * a[2];
                    float d3 = (sx + sc.w) - 2.0f * a[3];
                    unsigned long long p;
                    p = ((unsigned long long)__float_as_uint(d0) << 32) | (unsigned)(cbase + 0);
                    if (p < m) m = p;
                    p = ((unsigned long long)__float_as_uint(d1) << 32) | (unsigned)(cbase + 1);
                    if (p < m) m = p;
                    p = ((unsigned long long)__float_as_uint(d2) << 32) | (unsigned)(cbase + 2);
                    if (p < m) m = p;
                    p = ((unsigned long long)__float_as_uint(d3) << 32) | (unsigned)(cbase + 3);
                    if (p < m) m = p;
                }
            }
            unsigned long long o;
            o = __shfl_xor(m, 16); if (o < m) m = o;
            o = __shfl_xor(m, 32); if (o < m) m = o;
            if ((l >> 4) == 0) atomicMin(best + xrow, m);
        }
    }
}

// tiled coalesced gather/copy/stats: block = 64 n's x 256 d's
__global__ __launch_bounds__(256) void scatter_kernel(
    const float* __restrict__ x, const float* __restrict__ E,
    const unsigned long long* __restrict__ best,
    float* __restrict__ out, int* __restrict__ cs, float* __restrict__ dw)
{
    __shared__ float tx[64][68];
    __shared__ float te[64][68];
    __shared__ int sidx[64];

    const int blk = blockIdx.x;
    const int b   = blk >> 5;
    const int t0  = (blk & 31) * 64;
    const int tid = threadIdx.x;
    const int n0  = b * T_ + t0;

    if (tid < 64) {
        int ix = (int)(best[n0 + tid] & 0xffffffffu);
        sidx[tid] = ix;
        atomicAdd(cs + ix, 1);
    }
    __syncthreads();

    const int t4   = (tid & 15) * 4;
    const int dg   = tid >> 4;
    const int l    = tid & 63;
    const int w    = tid >> 6;
    const int nsub = l >> 4;
    const int dl4  = (l & 15) * 4;

    float* o0 = out;
    float* o1 = out + (size_t)N_ * D_;
    float* o2 = out + 2 * (size_t)N_ * D_;

    for (int dc = 0; dc < 4; dc++) {
        const int d0 = dc * 64;
        #pragma unroll
        for (int r = 0; r < 4; r++) {
            int d = r * 16 + dg;
            size_t gi = ((size_t)(b * D_ + d0 + d)) * T_ + t0 + t4;
            float4 v = *(const float4*)(x + gi);
            *(float4*)&tx[d][t4] = v;
            *(float4*)(o1 + gi) = v;
        }
        #pragma unroll
        for (int i = 0; i < 4; i++) {
            int nl  = w * 16 + i * 4 + nsub;
            int row = sidx[nl];
            float4 ev = *(const float4*)(E + (size_t)row * D_ + d0 + dl4);
            te[dl4 + 0][nl] = ev.x;
            te[dl4 + 1][nl] = ev.y;
            te[dl4 + 2][nl] = ev.z;
            te[dl4 + 3][nl] = ev.w;
        }
        __syncthreads();
        #pragma unroll
        for (int r = 0; r < 4; r++) {
            int d = r * 16 + dg;
            float4 v = *(const float4*)&te[d][t4];
            size_t gi = ((size_t)(b * D_ + d0 + d)) * T_ + t0 + t4;
            *(float4*)(o0 + gi) = v;
            *(float4*)(o2 + gi) = v;
        }
        #pragma unroll
        for (int i = 0; i < 16; i++) {
            int nl = w * 16 + i;
            atomicAdd(dw + (size_t)sidx[nl] * D_ + d0 + l, tx[l][nl]);
        }
        __syncthreads();
    }
}

__global__ __launch_bounds__(256) void finalize_kernel(
    const int* __restrict__ cs, const float* __restrict__ dw,
    float* __restrict__ out3)
{
    int k = blockIdx.x;
    int d = threadIdx.x;
    const float C = 0.00999999977648258209228515625f;
    float c   = (float)cs[k];
    float ecs = (c * C) / C;
    float edw = (dw[(size_t)k * D_ + d] * C) / C;
    float n = 16384.0f;
    float denom = (ecs + 1e-5f) / (n + (float)K_ * 1e-5f) * n;
    out3[(size_t)k * D_ + d] = edw / denom;
}

extern "C" void kernel_launch(void* const* d_in, const int* in_sizes, int n_in,
                              void* d_out, int out_size, void* d_ws, size_t ws_size,
                              hipStream_t stream) {
    const float* x = (const float*)d_in[0];
    const float* E = (const float*)d_in[1];
    float* out = (float*)d_out;

    char* ws = (char*)d_ws;
    unsigned long long* best = (unsigned long long*)(ws);
    int*   cs  = (int*)  (ws + 131072);
    float* dw  = (float*)(ws + 163840);
    float* sse = (float*)(ws + 8552448);
    float* ssx = (float*)(ws + 8585216);

    __bf16* X2 = (__bf16*)out;
    __bf16* E2 = (__bf16*)(out + 2 * (size_t)N_ * D_);

    hipMemsetAsync(best, 0xFF, (size_t)N_ * 8, stream);
    hipMemsetAsync(cs, 0, 8650752 - 131072, stream);   // cs+dw+sse+ssx contiguous

    hipFuncSetAttribute((const void*)dist_kernel,
                        hipFuncAttributeMaxDynamicSharedMemorySize, 131072);

    prep_e_kernel<<<K_ / 4, 256, 0, stream>>>(E, E2, sse);
    prep_x_kernel<<<1024, 256, 0, stream>>>(x, X2, ssx);
    dist_kernel<<<2048, 512, 131072, stream>>>(E2, X2, ssx, sse, best);
    scatter_kernel<<<256, 256, 0, stream>>>(x, E, best, out, cs, dw);
    finalize_kernel<<<K_, 256, 0, stream>>>(cs, dw, out + 3 * (size_t)N_ * D_);
}

// Round 8
// 228.997 us; speedup vs baseline: 4.7315x; 1.0014x over previous
//
#include <hip/hip_runtime.h>
#include <stdint.h>

#define B_ 8
#define D_ 256
#define T_ 2048
#define K_ 8192
#define N_ (B_*T_)   // 16384

typedef __attribute__((ext_vector_type(8))) __bf16 bf16x8;
typedef __attribute__((ext_vector_type(4))) __bf16 bf16x4;
typedef __attribute__((ext_vector_type(2))) __bf16 bf16x2;
typedef __attribute__((ext_vector_type(4))) float f32x4;

// ---------------- workspace layout ----------------
// best: u64[N]   off 0         (131072 B)
// cs:   int[K]   off 131072    (32768 B)
// dw:   f32[K*D] off 163840    (8388608 B)
// sse:  f32[K]   off 8552448   (32768 B)
// ssx:  f32[N]   off 8585216   (65536 B)
// Deduped GEMM panels in d_out (scratch until scatter runs):
//   X2 = [8][16384][64] bf16 (16.78 MB) at out+0      (panels 0-3 Xh, 4-7 Xl)
//   E2 = [8][8192][64]  bf16 (8.39 MB)  at out+32MB   (panels 0-3 El, 4-7 Eh)
// k-tile t (0..11): A panel = t>=8 ? t-4 : t ([El|Eh|Eh]); B panel = t&7 ([Xh|Xl|Xh])
// -> dot = El.Xh + Eh.Xl + Eh.Xh (identical products & per-acc order since R5)

__global__ __launch_bounds__(256) void prep_e_kernel(const float* __restrict__ E,
                                                     __bf16* __restrict__ E2,
                                                     float* __restrict__ sse) {
    int row  = blockIdx.x * 4 + (threadIdx.x >> 6);
    int lane = threadIdx.x & 63;
    float4 v = *(const float4*)(E + (size_t)row * D_ + lane * 4);
    __bf16 h0 = (__bf16)v.x, h1 = (__bf16)v.y, h2 = (__bf16)v.z, h3 = (__bf16)v.w;
    __bf16 l0 = (__bf16)(v.x - (float)h0), l1 = (__bf16)(v.y - (float)h1);
    __bf16 l2 = (__bf16)(v.z - (float)h2), l3 = (__bf16)(v.w - (float)h3);
    bf16x4 hv = {h0, h1, h2, h3};
    bf16x4 lv = {l0, l1, l2, l3};
    int p0  = lane >> 4;
    int col = (lane & 15) * 4;
    *(bf16x4*)(E2 + ((size_t)(p0    ) * K_ + row) * 64 + col) = lv;  // El
    *(bf16x4*)(E2 + ((size_t)(p0 + 4) * K_ + row) * 64 + col) = hv;  // Eh
    float s = __fadd_rn(__fadd_rn(__fmul_rn(v.x, v.x), __fmul_rn(v.y, v.y)),
                        __fadd_rn(__fmul_rn(v.z, v.z), __fmul_rn(v.w, v.w)));
    #pragma unroll
    for (int off = 32; off > 0; off >>= 1) s += __shfl_down(s, off);
    if (lane == 0) sse[row] = s;
}

__global__ __launch_bounds__(256) void prep_x_kernel(const float* __restrict__ x,
                                                     __bf16* __restrict__ X2,
                                                     float* __restrict__ ssx) {
    __shared__ float tile[64][65];
    __shared__ float part[64][4];
    int bidx = blockIdx.x;            // b(8) x dblk(4) x tblk(32)
    int b    = bidx >> 7;
    int dblk = (bidx >> 5) & 3;
    int tblk = bidx & 31;
    int d0 = dblk * 64, t0 = tblk * 64;
    const float* xp = x + (size_t)b * D_ * T_;
    {
        int tl = threadIdx.x & 63, th = threadIdx.x >> 6;
        float s = 0.f;
        #pragma unroll
        for (int i = 0; i < 16; i++) {
            int d = i * 4 + th;
            float v = xp[(size_t)(d0 + d) * T_ + t0 + tl];
            tile[d][tl] = v;
            s = __fadd_rn(s, __fmul_rn(v, v));
        }
        part[tl][th] = s;
    }
    __syncthreads();
    if (threadIdx.x < 64) {
        float tot = __fadd_rn(__fadd_rn(__fadd_rn(part[threadIdx.x][0],
                    part[threadIdx.x][1]), part[threadIdx.x][2]), part[threadIdx.x][3]);
        atomicAdd(ssx + b * T_ + t0 + threadIdx.x, tot);
    }
    {
        int dp = (threadIdx.x & 31) * 2, th = threadIdx.x >> 5;
        #pragma unroll
        for (int i = 0; i < 8; i++) {
            int t = i * 8 + th;
            float v0 = tile[dp][t], v1 = tile[dp + 1][t];
            __bf16 h0 = (__bf16)v0, h1 = (__bf16)v1;
            __bf16 q0 = (__bf16)(v0 - (float)h0), q1 = (__bf16)(v1 - (float)h1);
            size_t n = (size_t)b * T_ + t0 + t;
            bf16x2 hv = {h0, h1};
            bf16x2 lv = {q0, q1};
            *(bf16x2*)(X2 + ((size_t)(dblk    ) * N_ + n) * 64 + dp) = hv;  // Xh
            *(bf16x2*)(X2 + ((size_t)(dblk + 4) * N_ + n) * 64 + dp) = lv;  // Xl
        }
    }
}

// -------- 256x256 MFMA distance + argmin, 3-phase K-tile --------
// Per K-tile: ph1 {A-lo + B-lo reads | STAGE | 16 MFMA (0,0) | VMW(6)}
//             ph2 {B-hi reads        | STAGE | 16 MFMA (0,1)         }
//             ph3 {A-hi reads        | 2xSTAGE| 32 MFMA (1,1)+(1,0) | VMW(8)}
// No explicit lgkmcnt: ds_reads are compiler IR loads -> fine-grained waits.
// Reads of a phase are all consumed by its MFMA, so they drain before the
// trailing barrier -> >=2 barrier intervals before any LDS overwrite.

#define STAGE_A(kt, half, buf) do {                                             \
    const int pkt_ = ((kt) >= 8) ? (kt) - 4 : (kt);                             \
    const char* gp_ = (const char*)A2 + ((size_t)pkt_ * K_ + c0 + (half) * 128) * 128; \
    __bf16* lp_ = smem + ((buf) * 2 + (half)) * 8192;                           \
    __builtin_amdgcn_global_load_lds((const __attribute__((address_space(1))) void*)(gp_ + s1), \
        (__attribute__((address_space(3))) void*)(lp_ + wb1), 16, 0, 0);        \
    __builtin_amdgcn_global_load_lds((const __attribute__((address_space(1))) void*)(gp_ + s1 + 8192), \
        (__attribute__((address_space(3))) void*)(lp_ + wb2), 16, 0, 0);        \
  } while (0)

#define STAGE_B(kt, half, buf) do {                                             \
    const int pkt_ = (kt) & 7;                                                  \
    const char* gp_ = (const char*)B2 + ((size_t)pkt_ * N_ + r0 + (half) * 128) * 128; \
    __bf16* lp_ = smem + 32768 + ((buf) * 2 + (half)) * 8192;                   \
    __builtin_amdgcn_global_load_lds((const __attribute__((address_space(1))) void*)(gp_ + s1), \
        (__attribute__((address_space(3))) void*)(lp_ + wb1), 16, 0, 0);        \
    __builtin_amdgcn_global_load_lds((const __attribute__((address_space(1))) void*)(gp_ + s1 + 8192), \
        (__attribute__((address_space(3))) void*)(lp_ + wb2), 16, 0, 0);        \
  } while (0)

#define VMW(N) do { asm volatile("s_waitcnt vmcnt(" #N ")" ::: "memory");       \
                    __builtin_amdgcn_sched_barrier(0); } while (0)
#define NOPW ((void)0)

#define LOAD_A(DST, PA)                                                          \
    _Pragma("unroll")                                                            \
    for (int kk = 0; kk < 2; kk++) {                                             \
      _Pragma("unroll")                                                          \
      for (int i = 0; i < 4; i++) {                                              \
        int row_ = wm * 64 + i * 16 + (l & 15);                                  \
        int byt_ = (row_ * 128 + (kk * 4 + (l >> 4)) * 16) ^ ((row_ & 7) << 4);  \
        DST[kk][i] = *(const bf16x8*)((const char*)(PA) + byt_);                 \
      }                                                                          \
    }

#define LOAD_B(DST, PB)                                                          \
    _Pragma("unroll")                                                            \
    for (int kk = 0; kk < 2; kk++) {                                             \
      _Pragma("unroll")                                                          \
      for (int j = 0; j < 2; j++) {                                              \
        int row_ = wn * 32 + j * 16 + (l & 15);                                  \
        int byt_ = (row_ * 128 + (kk * 4 + (l >> 4)) * 16) ^ ((row_ & 7) << 4);  \
        DST[kk][j] = *(const bf16x8*)((const char*)(PB) + byt_);                 \
      }                                                                          \
    }

#define MFMA16(H, G, AF, BF)                                                     \
    _Pragma("unroll")                                                            \
    for (int kk = 0; kk < 2; kk++)                                               \
      _Pragma("unroll")                                                          \
      for (int i = 0; i < 4; i++)                                                \
        _Pragma("unroll")                                                        \
        for (int j = 0; j < 2; j++)                                              \
          acc[(H) * 4 + i][(G) * 2 + j] = __builtin_amdgcn_mfma_f32_16x16x32_bf16( \
              AF[kk][i], BF[kk][j], acc[(H) * 4 + i][(G) * 2 + j], 0, 0, 0)

#define PHX(LOADS, STAGE_STMT, MFMAS, WAIT_STMT) do {                            \
    LOADS;                                                                       \
    STAGE_STMT;                                                                  \
    __builtin_amdgcn_sched_barrier(0);                                           \
    __builtin_amdgcn_s_barrier();                                                \
    __builtin_amdgcn_s_setprio(1);                                               \
    MFMAS;                                                                       \
    __builtin_amdgcn_s_setprio(0);                                               \
    WAIT_STMT;                                                                   \
    __builtin_amdgcn_s_barrier();                                                \
    __builtin_amdgcn_sched_barrier(0);                                           \
  } while (0)

#define KTILE(bufi, S1, W1, S2, S3, S4, W3) do {                                 \
    const __bf16* paL_ = smem + ((bufi) * 2 + 0) * 8192;                         \
    const __bf16* paH_ = smem + ((bufi) * 2 + 1) * 8192;                         \
    const __bf16* pbL_ = smem + 32768 + ((bufi) * 2 + 0) * 8192;                 \
    const __bf16* pbH_ = smem + 32768 + ((bufi) * 2 + 1) * 8192;                 \
    bf16x8 af_[2][4], b0_[2][2], b1_[2][2];                                      \
    PHX({ LOAD_A(af_, paL_); LOAD_B(b0_, pbL_); }, S1,                           \
        MFMA16(0, 0, af_, b0_), W1);                                             \
    PHX({ LOAD_B(b1_, pbH_); }, S2,                                              \
        MFMA16(0, 1, af_, b1_), NOPW);                                           \
    PHX({ LOAD_A(af_, paH_); }, { S3; S4; },                                     \
        { MFMA16(1, 1, af_, b1_); MFMA16(1, 0, af_, b0_); }, W3);                \
  } while (0)

__global__ __launch_bounds__(512, 2) void dist_kernel(
    const __bf16* __restrict__ A2, const __bf16* __restrict__ B2,
    const float* __restrict__ ssx, const float* __restrict__ sse,
    unsigned long long* __restrict__ best)
{
    extern __shared__ __bf16 smem[];   // 65536 bf16 = 128 KiB

    const int tid = threadIdx.x;
    const int l   = tid & 63;
    const int w   = tid >> 6;        // 0..7
    const int wm  = w >> 2;          // M half within A-half (64 rows)
    const int wn  = w & 3;           // N quarter (32 cols)

    // L2-resident XCD mapping: XCD x owns c-tiles [4x,4x+4) x all 64 r-tiles.
    const int bid = blockIdx.x;
    const int xq  = bid & 7;
    const int i_  = bid >> 3;
    const int c0  = (xq * 4 + (i_ & 3)) * 256;
    const int r0  = (i_ >> 2) * 256;

    // staging addressing: linear LDS dest, inverse-swizzled global source
    const int o1  = tid * 16;
    const int s1  = o1 ^ (((tid >> 3) & 7) << 4);
    const int wb1 = w * 512;
    const int wb2 = w * 512 + 4096;

    f32x4 acc[8][4];
    #pragma unroll
    for (int i = 0; i < 8; i++)
        #pragma unroll
        for (int j = 0; j < 4; j++) acc[i][j] = (f32x4)0.f;

    // prologue: tile 0 (full) + tile 1 (halves 0) staged; wait 2 half-pairs
    STAGE_A(0, 0, 0); STAGE_B(0, 0, 0);
    STAGE_A(0, 1, 0); STAGE_B(0, 1, 0);
    STAGE_A(1, 0, 1); STAGE_B(1, 0, 1);
    VMW(8);
    __builtin_amdgcn_s_barrier();
    __builtin_amdgcn_sched_barrier(0);

    #pragma unroll 1
    for (int it = 0; it < 5; it++) {
        const int tX = 2 * it;
        KTILE(0, STAGE_A(tX + 1, 1, 1), VMW(6),
                 STAGE_B(tX + 1, 1, 1),
                 STAGE_A(tX + 2, 0, 0),
                 STAGE_B(tX + 2, 0, 0), VMW(8));
        KTILE(1, STAGE_A(tX + 2, 1, 0), VMW(6),
                 STAGE_B(tX + 2, 1, 0),
                 STAGE_A(tX + 3, 0, 1),
                 STAGE_B(tX + 3, 0, 1), VMW(8));
    }
    // peeled tail: tile 10 (buf0), tile 11 (buf1); drain 6->4->0
    KTILE(0, STAGE_A(11, 1, 1), VMW(6),
             STAGE_B(11, 1, 1),
             NOPW,
             NOPW, VMW(4));
    KTILE(1, NOPW, VMW(0),
             NOPW,
             NOPW,
             NOPW, NOPW);

    // epilogue: dist = (ssx + sse) - 2*dot, packed-u64 argmin (ties -> low idx)
    #pragma unroll
    for (int g = 0; g < 2; g++) {
        #pragma unroll
        for (int j = 0; j < 2; j++) {
            int xrow = r0 + g * 128 + wn * 32 + j * 16 + (l & 15);
            float sx = ssx[xrow];
            unsigned long long m = ~0ull;
            #pragma unroll
            for (int h = 0; h < 2; h++) {
                #pragma unroll
                for (int i = 0; i < 4; i++) {
                    int cbase = c0 + h * 128 + wm * 64 + i * 16 + (l >> 4) * 4;
                    float4 sc = *(const float4*)(sse + cbase);
                    f32x4 a = acc[h * 4 + i][g * 2 + j];
                    float d0 = (sx + sc.x) - 2.0f * a[0];
                    float d1 = (sx + sc.y) - 2.0f * a[1];
                    float d2 = (sx + sc.z) - 2.0f * a[2];
                    float d3 = (sx + sc.w) - 2.0f * a[3];
                    unsigned long long p;
                    p = ((unsigned long long)__float_as_uint(d0) << 32) | (unsigned)(cbase + 0);
                    if (p < m) m = p;
                    p = ((unsigned long long)__float_as_uint(d1) << 32) | (unsigned)(cbase + 1);
                    if (p < m) m = p;
                    p = ((unsigned long long)__float_as_uint(d2) << 32) | (unsigned)(cbase + 2);
                    if (p < m) m = p;
                    p = ((unsigned long long)__float_as_uint(d3) << 32) | (unsigned)(cbase + 3);
                    if (p < m) m = p;
                }
            }
            unsigned long long o;
            o = __shfl_xor(m, 16); if (o < m) m = o;
            o = __shfl_xor(m, 32); if (o < m) m = o;
            if ((l >> 4) == 0) atomicMin(best + xrow, m);
        }
    }
}

// tiled coalesced gather/copy/stats: block = 64 n's x 256 d's
__global__ __launch_bounds__(256) void scatter_kernel(
    const float* __restrict__ x, const float* __restrict__ E,
    const unsigned long long* __restrict__ best,
    float* __restrict__ out, int* __restrict__ cs, float* __restrict__ dw)
{
    __shared__ float tx[64][68];
    __shared__ float te[64][68];
    __shared__ int sidx[64];

    const int blk = blockIdx.x;
    const int b   = blk >> 5;
    const int t0  = (blk & 31) * 64;
    const int tid = threadIdx.x;
    const int n0  = b * T_ + t0;

    if (tid < 64) {
        int ix = (int)(best[n0 + tid] & 0xffffffffu);
        sidx[tid] = ix;
        atomicAdd(cs + ix, 1);
    }
    __syncthreads();

    const int t4   = (tid & 15) * 4;
    const int dg   = tid >> 4;
    const int l    = tid & 63;
    const int w    = tid >> 6;
    const int nsub = l >> 4;
    const int dl4  = (l & 15) * 4;

    float* o0 = out;
    float* o1 = out + (size_t)N_ * D_;
    float* o2 = out + 2 * (size_t)N_ * D_;

    for (int dc = 0; dc < 4; dc++) {
        const int d0 = dc * 64;
        #pragma unroll
        for (int r = 0; r < 4; r++) {
            int d = r * 16 + dg;
            size_t gi = ((size_t)(b * D_ + d0 + d)) * T_ + t0 + t4;
            float4 v = *(const float4*)(x + gi);
            *(float4*)&tx[d][t4] = v;
            *(float4*)(o1 + gi) = v;
        }
        #pragma unroll
        for (int i = 0; i < 4; i++) {
            int nl  = w * 16 + i * 4 + nsub;
            int row = sidx[nl];
            float4 ev = *(const float4*)(E + (size_t)row * D_ + d0 + dl4);
            te[dl4 + 0][nl] = ev.x;
            te[dl4 + 1][nl] = ev.y;
            te[dl4 + 2][nl] = ev.z;
            te[dl4 + 3][nl] = ev.w;
        }
        __syncthreads();
        #pragma unroll
        for (int r = 0; r < 4; r++) {
            int d = r * 16 + dg;
            float4 v = *(const float4*)&te[d][t4];
            size_t gi = ((size_t)(b * D_ + d0 + d)) * T_ + t0 + t4;
            *(float4*)(o0 + gi) = v;
            *(float4*)(o2 + gi) = v;
        }
        #pragma unroll
        for (int i = 0; i < 16; i++) {
            int nl = w * 16 + i;
            atomicAdd(dw + (size_t)sidx[nl] * D_ + d0 + l, tx[l][nl]);
        }
        __syncthreads();
    }
}

__global__ __launch_bounds__(256) void finalize_kernel(
    const int* __restrict__ cs, const float* __restrict__ dw,
    float* __restrict__ out3)
{
    int k = blockIdx.x;
    int d = threadIdx.x;
    const float C = 0.00999999977648258209228515625f;
    float c   = (float)cs[k];
    float ecs = (c * C) / C;
    float edw = (dw[(size_t)k * D_ + d] * C) / C;
    float n = 16384.0f;
    float denom = (ecs + 1e-5f) / (n + (float)K_ * 1e-5f) * n;
    out3[(size_t)k * D_ + d] = edw / denom;
}

extern "C" void kernel_launch(void* const* d_in, const int* in_sizes, int n_in,
                              void* d_out, int out_size, void* d_ws, size_t ws_size,
                              hipStream_t stream) {
    const float* x = (const float*)d_in[0];
    const float* E = (const float*)d_in[1];
    float* out = (float*)d_out;

    char* ws = (char*)d_ws;
    unsigned long long* best = (unsigned long long*)(ws);
    int*   cs  = (int*)  (ws + 131072);
    float* dw  = (float*)(ws + 163840);
    float* sse = (float*)(ws + 8552448);
    float* ssx = (float*)(ws + 8585216);

    __bf16* X2 = (__bf16*)out;
    __bf16* E2 = (__bf16*)(out + 2 * (size_t)N_ * D_);

    hipMemsetAsync(best, 0xFF, (size_t)N_ * 8, stream);
    hipMemsetAsync(cs, 0, 8650752 - 131072, stream);   // cs+dw+sse+ssx contiguous

    hipFuncSetAttribute((const void*)dist_kernel,
                        hipFuncAttributeMaxDynamicSharedMemorySize, 131072);

    prep_e_kernel<<<K_ / 4, 256, 0, stream>>>(E, E2, sse);
    prep_x_kernel<<<1024, 256, 0, stream>>>(x, X2, ssx);
    dist_kernel<<<2048, 512, 131072, stream>>>(E2, X2, ssx, sse, best);
    scatter_kernel<<<256, 256, 0, stream>>>(x, E, best, out, cs, dw);
    finalize_kernel<<<K_, 256, 0, stream>>>(cs, dw, out + 3 * (size_t)N_ * D_);
}